// Round 2
// baseline (2599.557 us; speedup 1.0000x reference)
//
#include <hip/hip_runtime.h>
#include <math.h>

#define NL     24
#define HIDDEN 512
#define H3     1536
#define NHEADS 16
#define HD     32
#define CAPCTX 2048
#define FFD    2048
#define NVOCAB 1025
#define GRID   256
#define NT     256
#define EPSLN  1e-5f
#define ISQ    0.17677669529663687f  /* 1/sqrt(32) */

// ---- agent-scope (LLC-coherent) data helpers -------------------------------
__device__ __forceinline__ float gld(const float* p){ return __hip_atomic_load(p, __ATOMIC_RELAXED, __HIP_MEMORY_SCOPE_AGENT); }
__device__ __forceinline__ void  gst(float* p, float v){ __hip_atomic_store(p, v, __ATOMIC_RELAXED, __HIP_MEMORY_SCOPE_AGENT); }

// ---- dataflow sync: release-add / acquire-poll -----------------------------
__device__ __forceinline__ void done_add(int* ctr, int tid){
  __syncthreads();   // each wave drains vmcnt(0) -> all block stores at LLC
  if (tid == 0) __hip_atomic_fetch_add(ctr, 1, __ATOMIC_RELEASE, __HIP_MEMORY_SCOPE_AGENT);
}
__device__ __forceinline__ void waitge(const int* ctr, int tgt){
  if (threadIdx.x == 0){
    int g = 0;
    while (__hip_atomic_load(ctr, __ATOMIC_ACQUIRE, __HIP_MEMORY_SCOPE_AGENT) < tgt){
      __builtin_amdgcn_s_sleep(1);
      if (++g > (1<<24)) break;   // safety: wrong answer beats a hang
    }
  }
  __syncthreads();
}
#define PIN() asm volatile("" ::: "memory")

struct LdsG { float xload[HIDDEN]; float xn[HIDDEN]; float red[16*17]; float r8[8]; };
struct LdsA { float q[HD]; float sc[128]; float e[128]; float v[128*33]; float red[NT]; };
struct LdsC { float m16[16]; float s16[16]; float o32[32]; };
union  Lds  { LdsG g; LdsA a; LdsC c; };

// ---- block reduction of two sums over 256 threads --------------------------
__device__ __forceinline__ void bsum2(float &a, float &bb, float* lds8, int tid){
  #pragma unroll
  for (int o=32;o;o>>=1){ a += __shfl_down(a,o); bb += __shfl_down(bb,o); }
  __syncthreads();
  if ((tid&63)==0){ int w=tid>>6; lds8[w]=a; lds8[4+w]=bb; }
  __syncthreads();
  a  = lds8[0]+lds8[1]+lds8[2]+lds8[3];
  bb = lds8[4]+lds8[5]+lds8[6]+lds8[7];
  __syncthreads();
}

// ---- t = x1 + b2 + sum(ff2 partials); xn = LN2(t) --------------------------
__device__ __forceinline__ void build_xn_from_t(const float* wx1, const float* wf2,
    const float* B2l, const float* NW2l, const float* NB2l,
    float* wx_out, LdsG* g, int tid)
{
  float s1=0.f, s2=0.f;
  for (int i=tid;i<HIDDEN;i+=NT){
    float t = gld(&wx1[i]) + B2l[i];
    #pragma unroll
    for (int rg=0; rg<8; rg++) t += gld(&wf2[rg*HIDDEN + i]);
    g->xload[i] = t; s1 += t; s2 += t*t;
  }
  bsum2(s1, s2, g->r8, tid);
  float mu   = s1*(1.f/HIDDEN);
  float rstd = rsqrtf(s2*(1.f/HIDDEN) - mu*mu + EPSLN);
  for (int i=tid;i<HIDDEN;i+=NT){
    float v = (g->xload[i]-mu)*rstd*NW2l[i] + NB2l[i];
    g->xn[i] = v;
    if (wx_out) gst(&wx_out[i], v);
  }
  __syncthreads();
}

// ---- 16-col GEMV from prefetched regs: thread (c=tid&15, s=tid>>4) ---------
template<int K>
__device__ __forceinline__ float dotred(const float* w, const float* xn, float* red, int tid){
  const int c = tid & 15, s = tid >> 4;
  float a = 0.f;
  #pragma unroll
  for (int k=0;k<K;k++) a += xn[s + 16*k] * w[k];
  red[s*17 + c] = a;
  __syncthreads();
  float d = 0.f;
  if (s == 0){
    #pragma unroll
    for (int k=0;k<16;k++) d += red[k*17 + c];
  }
  __syncthreads();
  return d;
}

__global__ __launch_bounds__(NT, 1)
void t2s_decode(const int* __restrict__ LT, const int* __restrict__ PI, const int* __restrict__ CL,
                const float* __restrict__ KC, const float* __restrict__ VC,
                const float* __restrict__ EMB, const float* __restrict__ PE,
                const float* __restrict__ XSc, const float* __restrict__ ALp,
                const float* __restrict__ QKVW, const float* __restrict__ QKVB,
                const float* __restrict__ OUTW, const float* __restrict__ OUTB,
                const float* __restrict__ NW1, const float* __restrict__ NB1,
                const float* __restrict__ NW2, const float* __restrict__ NB2,
                const float* __restrict__ W1, const float* __restrict__ B1,
                const float* __restrict__ W2, const float* __restrict__ B2,
                const float* __restrict__ PW, const float* __restrict__ PB,
                float* __restrict__ OUT, float* __restrict__ WS)
{
  __shared__ Lds L;
  const int b = blockIdx.x, tid = threadIdx.x;

  // counters: [0]=qkvdone [1..16]=headcnt [17]=opdone [18..25]=ff1cnt [26]=ff2cnt [27]=predcnt
  int* C = (int*)WS;
  float* F    = WS + 64;
  float* wx   = F;              // [512]   layer input x
  float* wx1  = F + 512;        // [512]   LN1 output
  float* wqkv = F + 1024;       // [1536]  q(pre-scaled)|k|v
  float* wop  = F + 2560;       // [16*512] out-proj K-slice partials
  float* wh   = F + 10752;      // [2048]  ff1 output (relu'd)
  float* wpart= F + 12800;      // [256*34] attn partials (m,S,o[32])
  float* wf2  = F + 21504;      // [8*512]  ff2 partials

  float* KO = OUT + 1029;
  float* VO = KO + (size_t)NL*CAPCTX*HIDDEN;

  const int token = LT[0], posi = PI[0], clen = CL[0], nlen = clen + 1;

  float pfA[32];   // qkv W slab     (blocks 0..95)
  float pfF1[32];  // ff1 W slab     (blocks 0..127)
  float pfF2[16];  // ff2 W slab     (all)
  float pfO[64];   // out-proj slab  (masters 240..255)

  // initial qkv prefetch (layer 0)
  if (b < 96){
    const float* Wq = QKVW + (size_t)(tid>>4)*H3 + (b<<4) + (tid&15);
    #pragma unroll
    for (int k=0;k<32;k++) pfA[k] = Wq[(size_t)k*16*H3];
    PIN();
  }

  for (int l=0; l<NL; l++){
    // ---- masters prefetch out-proj slab for this layer ---------------------
    if (b >= 240){
      const float* Wo = OUTW + (size_t)l*HIDDEN*HIDDEN + (size_t)((b-240)*HD)*HIDDEN + tid;
      #pragma unroll
      for (int d=0;d<32;d++){ pfO[d] = Wo[(size_t)d*HIDDEN]; pfO[32+d] = Wo[(size_t)d*HIDDEN + 256]; }
      PIN();
    }

    // ---- role A: qkv GEMV (0..95) | KV copy + tail zero (96..255) ----------
    if (b < 96){
      if (l == 0){
        float xs = XSc[0], al = ALp[0];
        for (int i=tid;i<HIDDEN;i+=NT){
          float v = EMB[(size_t)token*HIDDEN+i]*xs + al*PE[(size_t)posi*HIDDEN+i];
          L.g.xn[i] = v;
          if (b == 0) gst(&wx[i], v);
        }
        __syncthreads();
      } else {
        waitge(&C[26], 256*l);
        build_xn_from_t(wx1, wf2, B2+(size_t)(l-1)*HIDDEN,
                        NW2+(size_t)(l-1)*HIDDEN, NB2+(size_t)(l-1)*HIDDEN,
                        (b==0)? wx : nullptr, &L.g, tid);
      }
      float dsum = dotred<32>(pfA, L.g.xn, L.g.red, tid);
      if (tid < 16){
        int j = (b<<4) + tid;
        float val = dsum + QKVB[(size_t)l*H3 + j];
        if (j < HIDDEN) val *= ISQ;
        gst(&wqkv[j], val);
        if (j >= HIDDEN && j < 2*HIDDEN)  KO[((size_t)l*CAPCTX + clen)*HIDDEN + (j-HIDDEN)]   = val;
        else if (j >= 2*HIDDEN)           VO[((size_t)l*CAPCTX + clen)*HIDDEN + (j-2*HIDDEN)] = val;
      }
      done_add(&C[0], tid);
    } else {
      // no dependencies: copy rows<clen, zero rows>clen, for K and V
      const int t7 = tid & 127, halfr = tid >> 7;
      const float4 z4 = make_float4(0.f,0.f,0.f,0.f);
      for (int r0 = (b-96)*2; r0 < 4096; r0 += 320){
        int r = r0 + halfr;
        if (r < 4096){
          int p = r & 2047, isv = r >> 11;
          if (p != clen){
            float4* dst = (float4*)((isv ? VO : KO) + ((size_t)l*CAPCTX + p)*HIDDEN);
            if (p < clen){
              const float4* src = (const float4*)((isv ? VC : KC) + ((size_t)l*CAPCTX + p)*HIDDEN);
              dst[t7] = src[t7];
            } else {
              dst[t7] = z4;
            }
          }
        }
      }
    }

    // ---- prefetch ff1 / ff2 slabs (used after upcoming waits) --------------
    if (b < 128){
      const float* W1p = W1 + (size_t)l*HIDDEN*FFD + (size_t)(tid>>4)*FFD + (b<<4) + (tid&15);
      #pragma unroll
      for (int k=0;k<32;k++) pfF1[k] = W1p[(size_t)k*16*FFD];
    }
    {
      const int rg = b & 7, cg = b >> 3;
      const float* W2p = W2 + (size_t)l*FFD*HIDDEN + (size_t)(rg*256 + (tid>>4))*HIDDEN + (cg<<4) + (tid&15);
      #pragma unroll
      for (int k=0;k<16;k++) pfF2[k] = W2p[(size_t)k*16*HIDDEN];
    }
    PIN();

    // ---- role B: attention partials (all 256: head x 128-pos chunk) --------
    {
      const int h = b >> 4, cch = b & 15, p0 = cch << 7;
      waitge(&C[0], 96*(l+1));
      if (tid < HD) L.a.q[tid] = gld(&wqkv[h*HD + tid]);
      __syncthreads();
      const int p = p0 + (tid >> 1);
      const int half = tid & 1, dbase = half*16;
      const bool valid = (p < nlen);
      const size_t rowoff = ((size_t)l*CAPCTX + p)*HIDDEN + h*HD + dbase;
      float dotp = 0.f;
      float vbuf[16];
      if (valid){
        if (p == clen){
          #pragma unroll
          for (int k=0;k<16;k++){ float kv = gld(&wqkv[HIDDEN + h*HD + dbase + k]); dotp += kv * L.a.q[dbase+k]; }
        } else {
          const float4* src = (const float4*)(KC + rowoff);
          #pragma unroll
          for (int k4=0;k4<4;k4++){
            float4 v4 = src[k4];
            dotp += v4.x*L.a.q[dbase+4*k4] + v4.y*L.a.q[dbase+4*k4+1]
                  + v4.z*L.a.q[dbase+4*k4+2] + v4.w*L.a.q[dbase+4*k4+3];
          }
        }
      }
      dotp += __shfl_xor(dotp, 1);
      if (half == 0) L.a.sc[tid>>1] = valid ? dotp : -1e30f;
      if (valid){
        if (p == clen){
          #pragma unroll
          for (int k=0;k<16;k++) vbuf[k] = gld(&wqkv[2*HIDDEN + h*HD + dbase + k]);
        } else {
          const float4* srcv = (const float4*)(VC + rowoff);
          #pragma unroll
          for (int k4=0;k4<4;k4++){
            float4 v4 = srcv[k4];
            vbuf[4*k4]=v4.x; vbuf[4*k4+1]=v4.y; vbuf[4*k4+2]=v4.z; vbuf[4*k4+3]=v4.w;
          }
        }
      } else {
        #pragma unroll
        for (int k=0;k<16;k++) vbuf[k]=0.f;
      }
      #pragma unroll
      for (int k=0;k<16;k++) L.a.v[(p-p0)*33 + dbase + k] = vbuf[k];
      __syncthreads();
      float m = (tid < 128) ? L.a.sc[tid] : -1e30f;
      #pragma unroll
      for (int o=32;o;o>>=1) m = fmaxf(m, __shfl_xor(m, o));
      if ((tid&63)==0) L.a.red[tid>>6] = m;
      __syncthreads();
      m = fmaxf(fmaxf(L.a.red[0],L.a.red[1]), fmaxf(L.a.red[2],L.a.red[3]));
      __syncthreads();
      float e = 0.f;
      if (tid < 128){
        int pp = p0 + tid;
        e = (pp < nlen) ? expf(L.a.sc[tid] - m) : 0.f;
        L.a.e[tid] = e;
      }
      float ssum = e;
      #pragma unroll
      for (int o=32;o;o>>=1) ssum += __shfl_xor(ssum, o);
      if ((tid&63)==0) L.a.red[tid>>6] = ssum;
      __syncthreads();
      ssum = L.a.red[0]+L.a.red[1]+L.a.red[2]+L.a.red[3];
      __syncthreads();
      const int d = tid & 31, grp = tid >> 5;
      float oacc = 0.f;
      #pragma unroll
      for (int q2=0;q2<16;q2++){ int pp = (grp<<4) + q2; oacc += L.a.e[pp] * L.a.v[pp*33 + d]; }
      L.a.red[tid] = oacc;
      __syncthreads();
      float* rec = &wpart[(size_t)(h*16 + cch)*34];
      if (tid < 32){
        float o8 = 0.f;
        #pragma unroll
        for (int g=0; g<8; g++) o8 += L.a.red[tid + (g<<5)];
        gst(&rec[2+tid], o8);
      }
      if (tid == 0){ gst(&rec[0], m); gst(&rec[1], ssum); }
      done_add(&C[1+h], tid);
    }

    // ---- role C: per-head combine + out-proj K-slice (masters 240..255) ----
    if (b >= 240){
      const int h = b - 240;
      waitge(&C[1+h], 16*(l+1));
      const float* prt = &wpart[(size_t)(h*16)*34];
      if (tid < 16){ L.c.m16[tid] = gld(&prt[(size_t)tid*34]); L.c.s16[tid] = gld(&prt[(size_t)tid*34+1]); }
      __syncthreads();
      float M = L.c.m16[0];
      #pragma unroll
      for (int c=1;c<16;c++) M = fmaxf(M, L.c.m16[c]);
      float S = 0.f;
      #pragma unroll
      for (int c=0;c<16;c++) S += L.c.s16[c]*expf(L.c.m16[c]-M);
      if (tid < 32){
        float o = 0.f;
        #pragma unroll
        for (int c=0;c<16;c++) o += expf(L.c.m16[c]-M)*gld(&prt[(size_t)c*34+2+tid]);
        L.c.o32[tid] = o / S;
      }
      __syncthreads();
      float a0=0.f, a1=0.f;
      #pragma unroll
      for (int d=0; d<32; d++){ a0 += L.c.o32[d]*pfO[d]; a1 += L.c.o32[d]*pfO[32+d]; }
      gst(&wop[h*HIDDEN + tid], a0);
      gst(&wop[h*HIDDEN + 256 + tid], a1);
      done_add(&C[17], tid);
    }

    // ---- role D: reconstruct residual + LN1 + ff1 (blocks 0..127) ----------
    if (b < 128){
      waitge(&C[17], 16*(l+1));
      float s1=0.f, s2=0.f;
      for (int i=tid;i<HIDDEN;i+=NT){
        float t = gld(&wx[i]) + OUTB[(size_t)l*HIDDEN+i];
        #pragma unroll
        for (int h2=0;h2<16;h2++) t += gld(&wop[h2*HIDDEN+i]);
        L.g.xload[i]=t; s1+=t; s2+=t*t;
      }
      bsum2(s1,s2,L.g.r8,tid);
      float mu = s1*(1.f/HIDDEN), rstd = rsqrtf(s2*(1.f/HIDDEN)-mu*mu+EPSLN);
      for (int i=tid;i<HIDDEN;i+=NT){
        float xx = (L.g.xload[i]-mu)*rstd*NW1[(size_t)l*HIDDEN+i] + NB1[(size_t)l*HIDDEN+i];
        L.g.xn[i]=xx;
        if (b==0) gst(&wx1[i], xx);
      }
      __syncthreads();
      float dsum = dotred<32>(pfF1, L.g.xn, L.g.red, tid);
      if (tid < 16){
        int j = (b<<4) + tid;
        gst(&wh[j], fmaxf(dsum + B1[(size_t)l*FFD + j], 0.f));
      }
      done_add(&C[18+(b>>4)], tid);
    }

    // ---- role E: ff2 partials (all 256: cg=b>>3 cols, rg=b&7 rows) ---------
    {
      const int rg = b & 7, cg = b >> 3;
      waitge(&C[18+rg], 16*(l+1));
      L.g.xn[tid] = gld(&wh[rg*256 + tid]);
      __syncthreads();
      float dsum = dotred<16>(pfF2, L.g.xn, L.g.red, tid);
      if (tid < 16) gst(&wf2[rg*HIDDEN + (cg<<4) + tid], dsum);
      done_add(&C[26], tid);
    }

    // ---- prefetch next layer's qkv slab ------------------------------------
    if (b < 96 && l < NL-1){
      const float* Wq = QKVW + (size_t)(l+1)*HIDDEN*H3 + (size_t)(tid>>4)*H3 + (b<<4) + (tid&15);
      #pragma unroll
      for (int k=0;k<32;k++) pfA[k] = Wq[(size_t)k*16*H3];
      PIN();
    }
  }

  // ---- pred logits (blocks 0..64) ------------------------------------------
  if (b < 65){
    waitge(&C[26], 256*NL);
    build_xn_from_t(wx1, wf2, B2+(size_t)23*HIDDEN, NW2+(size_t)23*HIDDEN, NB2+(size_t)23*HIDDEN,
                    nullptr, &L.g, tid);
    const int v0 = b << 4;
    const int nrows = (b == 64) ? 1 : 16;
    const int rr = tid >> 4, s2l = tid & 15;
    if (rr < nrows){
      const float* row = PW + (size_t)(v0+rr)*HIDDEN;
      float acc = 0.f;
      #pragma unroll 8
      for (int mm=0; mm<32; mm++){ int i = s2l + (mm<<4); acc += L.g.xn[i] * row[i]; }
      #pragma unroll
      for (int o=1;o<16;o<<=1) acc += __shfl_xor(acc, o);
      if (s2l == 0) gst(&OUT[v0+rr], acc + PB[v0+rr]);
    }
    done_add(&C[27], tid);
  }

  // ---- final: argmax + scalars (block 0) -----------------------------------
  if (b == 0){
    waitge(&C[27], 65);
    float bv = -3.0e38f; int bi = 0;
    for (int v=tid; v<NVOCAB; v+=NT){
      float x = gld(&OUT[v]);
      if (x > bv){ bv = x; bi = v; }
    }
    L.g.xload[tid] = bv;
    ((int*)L.g.xn)[tid] = bi;
    __syncthreads();
    for (int step=128; step; step>>=1){
      if (tid < step){
        float ov2 = L.g.xload[tid+step]; int oi = ((int*)L.g.xn)[tid+step];
        float mv  = L.g.xload[tid];      int mi = ((int*)L.g.xn)[tid];
        if (ov2 > mv || (ov2 == mv && oi < mi)){ L.g.xload[tid]=ov2; ((int*)L.g.xn)[tid]=oi; }
      }
      __syncthreads();
    }
    if (tid == 0){
      int bi0 = ((int*)L.g.xn)[0];
      OUT[NVOCAB]   = (float)bi0;
      OUT[NVOCAB+1] = (bi0 == 1024) ? 1.f : 0.f;
      OUT[NVOCAB+2] = (float)nlen;
      OUT[NVOCAB+3] = (float)(posi + 1);
    }
  }
}

extern "C" void kernel_launch(void* const* d_in, const int* in_sizes, int n_in,
                              void* d_out, int out_size, void* d_ws, size_t ws_size,
                              hipStream_t stream) {
  (void)in_sizes; (void)n_in; (void)out_size; (void)ws_size;
  // zero the dataflow counters every call (replay-safe)
  hipMemsetAsync(d_ws, 0, 512, stream);
  t2s_decode<<<GRID, NT, 0, stream>>>(
    (const int*)d_in[0], (const int*)d_in[1], (const int*)d_in[2],
    (const float*)d_in[3], (const float*)d_in[4],
    (const float*)d_in[5], (const float*)d_in[6],
    (const float*)d_in[7], (const float*)d_in[8],
    (const float*)d_in[9], (const float*)d_in[10],
    (const float*)d_in[11], (const float*)d_in[12],
    (const float*)d_in[13], (const float*)d_in[14],
    (const float*)d_in[15], (const float*)d_in[16],
    (const float*)d_in[17], (const float*)d_in[18],
    (const float*)d_in[19], (const float*)d_in[20],
    (const float*)d_in[21], (const float*)d_in[22],
    (float*)d_out, (float*)d_ws);
}

// Round 3
// 761.472 us; speedup vs baseline: 3.4139x; 3.4139x over previous
//
#include <hip/hip_runtime.h>
#include <math.h>

#define NL     24
#define HIDDEN 512
#define H3     1536
#define NHEADS 16
#define HD     32
#define CAPCTX 2048
#define FFD    2048
#define NVOCAB 1025
#define GRID   256
#define NT     256
#define EPSLN  1e-5f
#define ISQ    0.17677669529663687f  /* 1/sqrt(32) */

// ---- agent-scope (LLC-coherent, relaxed) data helpers ----------------------
__device__ __forceinline__ float gld(const float* p){ return __hip_atomic_load(p, __ATOMIC_RELAXED, __HIP_MEMORY_SCOPE_AGENT); }
__device__ __forceinline__ void  gst(float* p, float v){ __hip_atomic_store(p, v, __ATOMIC_RELAXED, __HIP_MEMORY_SCOPE_AGENT); }

// ---- dataflow sync: RELAXED add / RELAXED spin (no cache-maintenance ops) --
__device__ __forceinline__ void done_add(int* ctr, int tid){
  __syncthreads();   // hipcc emits s_waitcnt vmcnt(0) before s_barrier -> stores at LLC
  if (tid == 0) __hip_atomic_fetch_add(ctr, 1, __ATOMIC_RELAXED, __HIP_MEMORY_SCOPE_AGENT);
}
__device__ __forceinline__ void waitge1(const int* c, int tgt){
  if (threadIdx.x == 0){
    int g = 0;
    while (__hip_atomic_load(c, __ATOMIC_RELAXED, __HIP_MEMORY_SCOPE_AGENT) < tgt){
      if (++g > (1<<24)) break;   // safety: never hang the harness
    }
  }
  __syncthreads();
}
__device__ __forceinline__ void waitgeN(const int* base, int n, int tgt){
  if ((int)threadIdx.x < n){
    const int* c = base + threadIdx.x*16;
    int g = 0;
    while (__hip_atomic_load(c, __ATOMIC_RELAXED, __HIP_MEMORY_SCOPE_AGENT) < tgt){
      if (++g > (1<<24)) break;
    }
  }
  __syncthreads();
}
#define PIN() asm volatile("" ::: "memory")

// counter indices (each on its own 64B line: offset = idx*16 ints)
#define QKV_C(g)  ((0 + (g))*16)   // 6 groups x 16 adders
#define HEAD_C(h) ((6 + (h))*16)   // 16 heads x 16 adders
#define OP_C      (22*16)          // 16 adders
#define FF1_C(g)  ((23 + (g))*16)  // 8 groups x 16 adders
#define FF2_C(g)  ((31 + (g))*16)  // 8 groups x 32 adders
#define PRED_C    (39*16)          // 65 adders

struct LdsG { float xload[HIDDEN]; float xn[HIDDEN]; float red[16*17]; float r8[8]; };
struct LdsA { float q[HD]; float sc[128]; float e[128]; float v[128*33]; float red[NT]; };
struct LdsC { float m16[16]; float s16[16]; float o32[32]; };
union  Lds  { LdsG g; LdsA a; LdsC c; };

// ---- block reduction of two sums over 256 threads --------------------------
__device__ __forceinline__ void bsum2(float &a, float &bb, float* lds8, int tid){
  #pragma unroll
  for (int o=32;o;o>>=1){ a += __shfl_down(a,o); bb += __shfl_down(bb,o); }
  __syncthreads();
  if ((tid&63)==0){ int w=tid>>6; lds8[w]=a; lds8[4+w]=bb; }
  __syncthreads();
  a  = lds8[0]+lds8[1]+lds8[2]+lds8[3];
  bb = lds8[4]+lds8[5]+lds8[6]+lds8[7];
  __syncthreads();
}

// ---- t = x1 + b2 + sum(ff2 partials); xn = LN2(t) --------------------------
__device__ __forceinline__ void build_xn_from_t(const float* wx1, const float* wf2,
    const float* B2l, const float* NW2l, const float* NB2l,
    float* wx_out, LdsG* g, int tid)
{
  float s1=0.f, s2=0.f;
  for (int i=tid;i<HIDDEN;i+=NT){
    float t = gld(&wx1[i]) + B2l[i];
    #pragma unroll
    for (int rg=0; rg<8; rg++) t += gld(&wf2[rg*HIDDEN + i]);
    g->xload[i] = t; s1 += t; s2 += t*t;
  }
  bsum2(s1, s2, g->r8, tid);
  float mu   = s1*(1.f/HIDDEN);
  float rstd = rsqrtf(s2*(1.f/HIDDEN) - mu*mu + EPSLN);
  for (int i=tid;i<HIDDEN;i+=NT){
    float v = (g->xload[i]-mu)*rstd*NW2l[i] + NB2l[i];
    g->xn[i] = v;
    if (wx_out) gst(&wx_out[i], v);
  }
  __syncthreads();
}

// ---- 16-col GEMV from prefetched regs: thread (c=tid&15, s=tid>>4) ---------
template<int K>
__device__ __forceinline__ float dotred(const float* w, const float* xn, float* red, int tid){
  const int c = tid & 15, s = tid >> 4;
  float a = 0.f;
  #pragma unroll
  for (int k=0;k<K;k++) a += xn[s + 16*k] * w[k];
  red[s*17 + c] = a;
  __syncthreads();
  float d = 0.f;
  if (s == 0){
    #pragma unroll
    for (int k=0;k<16;k++) d += red[k*17 + c];
  }
  __syncthreads();
  return d;
}

__global__ __launch_bounds__(NT, 1)
void t2s_decode(const int* __restrict__ LT, const int* __restrict__ PI, const int* __restrict__ CL,
                const float* __restrict__ KC, const float* __restrict__ VC,
                const float* __restrict__ EMB, const float* __restrict__ PE,
                const float* __restrict__ XSc, const float* __restrict__ ALp,
                const float* __restrict__ QKVW, const float* __restrict__ QKVB,
                const float* __restrict__ OUTW, const float* __restrict__ OUTB,
                const float* __restrict__ NW1, const float* __restrict__ NB1,
                const float* __restrict__ NW2, const float* __restrict__ NB2,
                const float* __restrict__ W1, const float* __restrict__ B1,
                const float* __restrict__ W2, const float* __restrict__ B2,
                const float* __restrict__ PW, const float* __restrict__ PB,
                float* __restrict__ OUT, float* __restrict__ WS)
{
  __shared__ Lds L;
  const int b = blockIdx.x, tid = threadIdx.x;

  int* C = (int*)WS;            // 40 counters x 16 ints (zeroed by memset)
  float* F    = WS + 1024;
  float* wx   = F;              // [512]   layer input x
  float* wx1  = F + 512;        // [512]   LN1 output
  float* wqkv = F + 1024;       // [1536]  q(pre-scaled)|k|v
  float* wop  = F + 2560;       // [16*512] out-proj K-slice partials
  float* wh   = F + 10752;      // [2048]  ff1 output (relu'd)
  float* wpart= F + 12800;      // [256*34] attn partials (m,S,o[32])
  float* wf2  = F + 21504;      // [8*512]  ff2 partials

  float* KO = OUT + 1029;
  float* VO = KO + (size_t)NL*CAPCTX*HIDDEN;

  const int token = LT[0], posi = PI[0], clen = CL[0], nlen = clen + 1;

  float pfA[32];   // qkv W slab     (blocks 0..95)
  float pfF1[32];  // ff1 W slab     (blocks 0..127)
  float pfF2[16];  // ff2 W slab     (all)
  float pfO[64];   // out-proj slab  (masters 240..255)

  // initial qkv prefetch (layer 0)
  if (b < 96){
    const float* Wq = QKVW + (size_t)(tid>>4)*H3 + (b<<4) + (tid&15);
    #pragma unroll
    for (int k=0;k<32;k++) pfA[k] = Wq[(size_t)k*16*H3];
    PIN();
  }

  for (int l=0; l<NL; l++){
    // ---- masters prefetch out-proj slab for this layer ---------------------
    if (b >= 240){
      const float* Wo = OUTW + (size_t)l*HIDDEN*HIDDEN + (size_t)((b-240)*HD)*HIDDEN + tid;
      #pragma unroll
      for (int d=0;d<32;d++){ pfO[d] = Wo[(size_t)d*HIDDEN]; pfO[32+d] = Wo[(size_t)d*HIDDEN + 256]; }
      PIN();
    }

    // ---- role A: qkv GEMV (blocks 0..95) -----------------------------------
    if (b < 96){
      if (l == 0){
        float xs = XSc[0], al = ALp[0];
        for (int i=tid;i<HIDDEN;i+=NT){
          float v = EMB[(size_t)token*HIDDEN+i]*xs + al*PE[(size_t)posi*HIDDEN+i];
          L.g.xn[i] = v;
          if (b == 0) gst(&wx[i], v);
        }
        __syncthreads();
      } else {
        waitgeN(C + FF2_C(0), 8, 32*l);
        build_xn_from_t(wx1, wf2, B2+(size_t)(l-1)*HIDDEN,
                        NW2+(size_t)(l-1)*HIDDEN, NB2+(size_t)(l-1)*HIDDEN,
                        (b==0)? wx : nullptr, &L.g, tid);
      }
      float dsum = dotred<32>(pfA, L.g.xn, L.g.red, tid);
      if (tid < 16){
        int j = (b<<4) + tid;
        float val = dsum + QKVB[(size_t)l*H3 + j];
        if (j < HIDDEN) val *= ISQ;
        gst(&wqkv[j], val);
        if (j >= HIDDEN && j < 2*HIDDEN)  KO[((size_t)l*CAPCTX + clen)*HIDDEN + (j-HIDDEN)]   = val;
        else if (j >= 2*HIDDEN)           VO[((size_t)l*CAPCTX + clen)*HIDDEN + (j-2*HIDDEN)] = val;
      }
      done_add(&C[QKV_C(b>>4)], tid);
    }

    // ---- prefetch ff1 / ff2 slabs (used after upcoming waits) --------------
    if (b < 128){
      const float* W1p = W1 + (size_t)l*HIDDEN*FFD + (size_t)(tid>>4)*FFD + (b<<4) + (tid&15);
      #pragma unroll
      for (int k=0;k<32;k++) pfF1[k] = W1p[(size_t)k*16*FFD];
    }
    {
      const int rg = b & 7, cg = b >> 3;
      const float* W2p = W2 + (size_t)l*FFD*HIDDEN + (size_t)(rg*256 + (tid>>4))*HIDDEN + (cg<<4) + (tid&15);
      #pragma unroll
      for (int k=0;k<16;k++) pfF2[k] = W2p[(size_t)k*16*HIDDEN];
    }
    PIN();

    // ---- role B: attention partials (all 256: head x 128-pos chunk) --------
    {
      const int h = b >> 4, cch = b & 15, p0 = cch << 7;
      waitgeN(C + QKV_C(0), 6, 16*(l+1));
      if (tid < HD) L.a.q[tid] = gld(&wqkv[h*HD + tid]);
      __syncthreads();
      const int p = p0 + (tid >> 1);
      const int half = tid & 1, dbase = half*16;
      const bool valid = (p < nlen);
      const size_t rowoff = ((size_t)l*CAPCTX + p)*HIDDEN + h*HD + dbase;
      float dotp = 0.f;
      float vbuf[16];
      if (valid){
        if (p == clen){
          #pragma unroll
          for (int k=0;k<16;k++){ float kv = gld(&wqkv[HIDDEN + h*HD + dbase + k]); dotp += kv * L.a.q[dbase+k]; }
        } else {
          const float4* src = (const float4*)(KC + rowoff);
          #pragma unroll
          for (int k4=0;k4<4;k4++){
            float4 v4 = src[k4];
            dotp += v4.x*L.a.q[dbase+4*k4] + v4.y*L.a.q[dbase+4*k4+1]
                  + v4.z*L.a.q[dbase+4*k4+2] + v4.w*L.a.q[dbase+4*k4+3];
          }
        }
      }
      dotp += __shfl_xor(dotp, 1);
      if (half == 0) L.a.sc[tid>>1] = valid ? dotp : -1e30f;
      if (valid){
        if (p == clen){
          #pragma unroll
          for (int k=0;k<16;k++) vbuf[k] = gld(&wqkv[2*HIDDEN + h*HD + dbase + k]);
        } else {
          const float4* srcv = (const float4*)(VC + rowoff);
          #pragma unroll
          for (int k4=0;k4<4;k4++){
            float4 v4 = srcv[k4];
            vbuf[4*k4]=v4.x; vbuf[4*k4+1]=v4.y; vbuf[4*k4+2]=v4.z; vbuf[4*k4+3]=v4.w;
          }
        }
      } else {
        #pragma unroll
        for (int k=0;k<16;k++) vbuf[k]=0.f;
      }
      #pragma unroll
      for (int k=0;k<16;k++) L.a.v[(p-p0)*33 + dbase + k] = vbuf[k];
      __syncthreads();
      float m = (tid < 128) ? L.a.sc[tid] : -1e30f;
      #pragma unroll
      for (int o=32;o;o>>=1) m = fmaxf(m, __shfl_xor(m, o));
      if ((tid&63)==0) L.a.red[tid>>6] = m;
      __syncthreads();
      m = fmaxf(fmaxf(L.a.red[0],L.a.red[1]), fmaxf(L.a.red[2],L.a.red[3]));
      __syncthreads();
      float e = 0.f;
      if (tid < 128){
        int pp = p0 + tid;
        e = (pp < nlen) ? expf(L.a.sc[tid] - m) : 0.f;
        L.a.e[tid] = e;
      }
      float ssum = e;
      #pragma unroll
      for (int o=32;o;o>>=1) ssum += __shfl_xor(ssum, o);
      if ((tid&63)==0) L.a.red[tid>>6] = ssum;
      __syncthreads();
      ssum = L.a.red[0]+L.a.red[1]+L.a.red[2]+L.a.red[3];
      __syncthreads();
      const int d = tid & 31, grp = tid >> 5;
      float oacc = 0.f;
      #pragma unroll
      for (int q2=0;q2<16;q2++){ int pp = (grp<<4) + q2; oacc += L.a.e[pp] * L.a.v[pp*33 + d]; }
      L.a.red[tid] = oacc;
      __syncthreads();
      float* rec = &wpart[(size_t)(h*16 + cch)*34];
      if (tid < 32){
        float o8 = 0.f;
        #pragma unroll
        for (int g=0; g<8; g++) o8 += L.a.red[tid + (g<<5)];
        gst(&rec[2+tid], o8);
      }
      if (tid == 0){ gst(&rec[0], m); gst(&rec[1], ssum); }
      done_add(&C[HEAD_C(h)], tid);
    }

    // ---- KV copy + tail zero: blocks 128..239, hidden under combine/ff1 ----
    if (b >= 128 && b < 240){
      const int t7 = tid & 127, halfr = tid >> 7;
      const float4 z4 = make_float4(0.f,0.f,0.f,0.f);
      for (int r0 = (b-128)*2; r0 < 4096; r0 += 224){
        int r = r0 + halfr;
        if (r < 4096){
          int p = r & 2047, isv = r >> 11;
          if (p != clen){
            float4* dst = (float4*)((isv ? VO : KO) + ((size_t)l*CAPCTX + p)*HIDDEN);
            if (p < clen){
              const float4* src = (const float4*)((isv ? VC : KC) + ((size_t)l*CAPCTX + p)*HIDDEN);
              dst[t7] = src[t7];
            } else {
              dst[t7] = z4;
            }
          }
        }
      }
    }

    // ---- role C: per-head combine + out-proj K-slice (masters 240..255) ----
    if (b >= 240){
      const int h = b - 240;
      waitge1(&C[HEAD_C(h)], 16*(l+1));
      const float* prt = &wpart[(size_t)(h*16)*34];
      if (tid < 16){ L.c.m16[tid] = gld(&prt[(size_t)tid*34]); L.c.s16[tid] = gld(&prt[(size_t)tid*34+1]); }
      __syncthreads();
      float M = L.c.m16[0];
      #pragma unroll
      for (int c=1;c<16;c++) M = fmaxf(M, L.c.m16[c]);
      float S = 0.f;
      #pragma unroll
      for (int c=0;c<16;c++) S += L.c.s16[c]*expf(L.c.m16[c]-M);
      if (tid < 32){
        float o = 0.f;
        #pragma unroll
        for (int c=0;c<16;c++) o += expf(L.c.m16[c]-M)*gld(&prt[(size_t)c*34+2+tid]);
        L.c.o32[tid] = o / S;
      }
      __syncthreads();
      float a0=0.f, a1=0.f;
      #pragma unroll
      for (int d=0; d<32; d++){ a0 += L.c.o32[d]*pfO[d]; a1 += L.c.o32[d]*pfO[32+d]; }
      gst(&wop[h*HIDDEN + tid], a0);
      gst(&wop[h*HIDDEN + 256 + tid], a1);
      done_add(&C[OP_C], tid);
    }

    // ---- role D: reconstruct residual + LN1 + ff1 (blocks 0..127) ----------
    if (b < 128){
      waitge1(&C[OP_C], 16*(l+1));
      float s1=0.f, s2=0.f;
      for (int i=tid;i<HIDDEN;i+=NT){
        float t = gld(&wx[i]) + OUTB[(size_t)l*HIDDEN+i];
        #pragma unroll
        for (int h2=0;h2<16;h2++) t += gld(&wop[h2*HIDDEN+i]);
        L.g.xload[i]=t; s1+=t; s2+=t*t;
      }
      bsum2(s1,s2,L.g.r8,tid);
      float mu = s1*(1.f/HIDDEN), rstd = rsqrtf(s2*(1.f/HIDDEN)-mu*mu+EPSLN);
      for (int i=tid;i<HIDDEN;i+=NT){
        float xx = (L.g.xload[i]-mu)*rstd*NW1[(size_t)l*HIDDEN+i] + NB1[(size_t)l*HIDDEN+i];
        L.g.xn[i]=xx;
        if (b==0) gst(&wx1[i], xx);
      }
      __syncthreads();
      float dsum = dotred<32>(pfF1, L.g.xn, L.g.red, tid);
      if (tid < 16){
        int j = (b<<4) + tid;
        gst(&wh[j], fmaxf(dsum + B1[(size_t)l*FFD + j], 0.f));
      }
      done_add(&C[FF1_C(b>>4)], tid);
    }

    // ---- role E: ff2 partials (all 256: cg=b>>3 cols, rg=b&7 rows) ---------
    {
      const int rg = b & 7, cg = b >> 3;
      waitge1(&C[FF1_C(rg)], 16*(l+1));
      L.g.xn[tid] = gld(&wh[rg*256 + tid]);
      __syncthreads();
      float dsum = dotred<16>(pfF2, L.g.xn, L.g.red, tid);
      if (tid < 16) gst(&wf2[rg*HIDDEN + (cg<<4) + tid], dsum);
      done_add(&C[FF2_C(rg)], tid);
    }

    // ---- prefetch next layer's qkv slab ------------------------------------
    if (b < 96 && l < NL-1){
      const float* Wq = QKVW + (size_t)(l+1)*HIDDEN*H3 + (size_t)(tid>>4)*H3 + (b<<4) + (tid&15);
      #pragma unroll
      for (int k=0;k<32;k++) pfA[k] = Wq[(size_t)k*16*H3];
      PIN();
    }
  }

  // ---- pred logits (blocks 0..64) ------------------------------------------
  if (b < 65){
    const int v0 = b << 4;
    const int nrows = (b == 64) ? 1 : 16;
    const int rr = tid >> 4, s2l = tid & 15;
    float pfP[32];
    if (rr < nrows){
      const float* row = PW + (size_t)(v0+rr)*HIDDEN;
      #pragma unroll
      for (int mm=0; mm<32; mm++) pfP[mm] = row[s2l + (mm<<4)];
    }
    PIN();
    waitgeN(C + FF2_C(0), 8, 32*NL);
    build_xn_from_t(wx1, wf2, B2+(size_t)23*HIDDEN, NW2+(size_t)23*HIDDEN, NB2+(size_t)23*HIDDEN,
                    nullptr, &L.g, tid);
    if (rr < nrows){
      float acc = 0.f;
      #pragma unroll
      for (int mm=0; mm<32; mm++) acc += L.g.xn[s2l + (mm<<4)] * pfP[mm];
      #pragma unroll
      for (int o=1;o<16;o<<=1) acc += __shfl_xor(acc, o);
      if (s2l == 0) gst(&OUT[v0+rr], acc + PB[v0+rr]);
    }
    done_add(&C[PRED_C], tid);
  }

  // ---- final: argmax + scalars (block 0) -----------------------------------
  if (b == 0){
    waitge1(&C[PRED_C], 65);
    float bv = -3.0e38f; int bi = 0;
    for (int v=tid; v<NVOCAB; v+=NT){
      float x = gld(&OUT[v]);
      if (x > bv){ bv = x; bi = v; }
    }
    L.g.xload[tid] = bv;
    ((int*)L.g.xn)[tid] = bi;
    __syncthreads();
    for (int step=128; step; step>>=1){
      if (tid < step){
        float ov2 = L.g.xload[tid+step]; int oi = ((int*)L.g.xn)[tid+step];
        float mv  = L.g.xload[tid];      int mi = ((int*)L.g.xn)[tid];
        if (ov2 > mv || (ov2 == mv && oi < mi)){ L.g.xload[tid]=ov2; ((int*)L.g.xn)[tid]=oi; }
      }
      __syncthreads();
    }
    if (tid == 0){
      int bi0 = ((int*)L.g.xn)[0];
      OUT[NVOCAB]   = (float)bi0;
      OUT[NVOCAB+1] = (bi0 == 1024) ? 1.f : 0.f;
      OUT[NVOCAB+2] = (float)nlen;
      OUT[NVOCAB+3] = (float)(posi + 1);
    }
  }
}

extern "C" void kernel_launch(void* const* d_in, const int* in_sizes, int n_in,
                              void* d_out, int out_size, void* d_ws, size_t ws_size,
                              hipStream_t stream) {
  (void)in_sizes; (void)n_in; (void)out_size; (void)ws_size;
  // zero the dataflow counters every call (replay-safe)
  hipMemsetAsync(d_ws, 0, 4096, stream);
  t2s_decode<<<GRID, NT, 0, stream>>>(
    (const int*)d_in[0], (const int*)d_in[1], (const int*)d_in[2],
    (const float*)d_in[3], (const float*)d_in[4],
    (const float*)d_in[5], (const float*)d_in[6],
    (const float*)d_in[7], (const float*)d_in[8],
    (const float*)d_in[9], (const float*)d_in[10],
    (const float*)d_in[11], (const float*)d_in[12],
    (const float*)d_in[13], (const float*)d_in[14],
    (const float*)d_in[15], (const float*)d_in[16],
    (const float*)d_in[17], (const float*)d_in[18],
    (const float*)d_in[19], (const float*)d_in[20],
    (const float*)d_in[21], (const float*)d_in[22],
    (float*)d_out, (float*)d_ws);
}

// Round 4
// 714.521 us; speedup vs baseline: 3.6382x; 1.0657x over previous
//
#include <hip/hip_runtime.h>
#include <math.h>

#define NL     24
#define HIDDEN 512
#define H3     1536
#define NHEADS 16
#define HD     32
#define CAPCTX 2048
#define FFD    2048
#define NVOCAB 1025
#define GRID   256
#define NT     256
#define EPSLN  1e-5f
#define ISQ    0.17677669529663687f  /* 1/sqrt(32) */

// ---- agent-scope (LLC-coherent, relaxed) helpers ---------------------------
__device__ __forceinline__ float gld(const float* p){ return __hip_atomic_load(p, __ATOMIC_RELAXED, __HIP_MEMORY_SCOPE_AGENT); }
__device__ __forceinline__ void  gst(float* p, float v){ __hip_atomic_store(p, v, __ATOMIC_RELAXED, __HIP_MEMORY_SCOPE_AGENT); }
__device__ __forceinline__ int   ild(const int* p){ return __hip_atomic_load(p, __ATOMIC_RELAXED, __HIP_MEMORY_SCOPE_AGENT); }
__device__ __forceinline__ void  ist(int* p, int v){ __hip_atomic_store(p, v, __ATOMIC_RELAXED, __HIP_MEMORY_SCOPE_AGENT); }

__device__ __forceinline__ void done_add(int* ctr, int tid){
  __syncthreads();   // drains vmcnt(0): all block stores at LLC before the add
  if (tid == 0) __hip_atomic_fetch_add(ctr, 1, __ATOMIC_RELAXED, __HIP_MEMORY_SCOPE_AGENT);
}
__device__ __forceinline__ void waitge1(const int* c, int tgt){
  if (threadIdx.x == 0){
    int g = 0;
    while (__hip_atomic_load(c, __ATOMIC_RELAXED, __HIP_MEMORY_SCOPE_AGENT) < tgt){
      if (++g > (1<<25)) break;   // safety: never hang the harness
    }
  }
  __syncthreads();
}
__device__ __forceinline__ void waitgeN(const int* base, int n, int tgt){
  if ((int)threadIdx.x < n){
    const int* c = base + threadIdx.x*16;
    int g = 0;
    while (__hip_atomic_load(c, __ATOMIC_RELAXED, __HIP_MEMORY_SCOPE_AGENT) < tgt){
      if (++g > (1<<25)) break;
    }
  }
  __syncthreads();
}
#define PIN() asm volatile("" ::: "memory")

// counter map (units of int; each counter on its own 64B line)
#define QFLAG(b)  ((b)*16)        // 96 per-block qkv flags (value = l+1)
#define HEAD_C(h) ((96+(h))*16)   // 16 head counters (16 adds/layer)
#define OP_C      (112*16)        // out-proj done (16 adds/layer)
#define FF1_C(g)  ((113+(g))*16)  // 8 groups (16 adds/layer)
#define FF2_C(g)  ((121+(g))*16)  // 8 groups (32 adds/layer)
#define PRED_C    (129*16)        // 65 adds

struct LdsG { float xload[HIDDEN]; float xn[HIDDEN]; float red[16*17]; float r8[8]; };
struct LdsA { float q[HD]; float sc[128]; float e[128]; float v[128*33]; float red[NT]; };
struct LdsC { float m16[16]; float s16[16]; float o32[32]; };
union  Lds  { LdsG g; LdsA a; LdsC c; };

__device__ __forceinline__ void bsum2(float &a, float &bb, float* lds8, int tid){
  #pragma unroll
  for (int o=32;o;o>>=1){ a += __shfl_down(a,o); bb += __shfl_down(bb,o); }
  __syncthreads();
  if ((tid&63)==0){ int w=tid>>6; lds8[w]=a; lds8[4+w]=bb; }
  __syncthreads();
  a  = lds8[0]+lds8[1]+lds8[2]+lds8[3];
  bb = lds8[4]+lds8[5]+lds8[6]+lds8[7];
  __syncthreads();
}

template<int K>
__device__ __forceinline__ float dotred(const float* w, const float* xn, float* red, int tid){
  const int c = tid & 15, s = tid >> 4;
  float a = 0.f;
  #pragma unroll
  for (int k=0;k<K;k++) a += xn[s + 16*k] * w[k];
  red[s*17 + c] = a;
  __syncthreads();
  float d = 0.f;
  if (s == 0){
    #pragma unroll
    for (int k=0;k<16;k++) d += red[k*17 + c];
  }
  __syncthreads();
  return d;
}

// ---- attention task (head h, chunk c): waits only its 6 qkv producers ------
__device__ __forceinline__ void attn_task(int l, int h, int c, int clen, int nlen,
    const float* __restrict__ KC, const float* __restrict__ VC,
    const float* wqkv, float* wpart, int* C, LdsA* A, int tid)
{
  if (tid < 6){
    int pb = (tid>>1)*32 + 2*h + (tid&1);   // {2h,2h+1, 32+2h,33+2h, 64+2h,65+2h}
    const int* f = C + QFLAG(pb);
    int g = 0;
    while (ild(f) < l+1){ if (++g > (1<<25)) break; }
  }
  __syncthreads();
  const int p0 = c << 7;
  if (tid < HD) A->q[tid] = gld(&wqkv[h*HD + tid]);
  __syncthreads();
  const int p = p0 + (tid >> 1);
  const int half = tid & 1, dbase = half*16;
  const bool valid = (p < nlen);
  const size_t rowoff = ((size_t)l*CAPCTX + p)*HIDDEN + h*HD + dbase;
  float dotp = 0.f;
  float vbuf[16];
  if (valid){
    if (p == clen){
      #pragma unroll
      for (int k=0;k<16;k++){ float kv = gld(&wqkv[HIDDEN + h*HD + dbase + k]); dotp += kv * A->q[dbase+k]; }
    } else {
      const float4* src = (const float4*)(KC + rowoff);
      #pragma unroll
      for (int k4=0;k4<4;k4++){
        float4 v4 = src[k4];
        dotp += v4.x*A->q[dbase+4*k4] + v4.y*A->q[dbase+4*k4+1]
              + v4.z*A->q[dbase+4*k4+2] + v4.w*A->q[dbase+4*k4+3];
      }
    }
  }
  dotp += __shfl_xor(dotp, 1);
  if (half == 0) A->sc[tid>>1] = valid ? dotp : -1e30f;
  if (valid){
    if (p == clen){
      #pragma unroll
      for (int k=0;k<16;k++) vbuf[k] = gld(&wqkv[2*HIDDEN + h*HD + dbase + k]);
    } else {
      const float4* srcv = (const float4*)(VC + rowoff);
      #pragma unroll
      for (int k4=0;k4<4;k4++){
        float4 v4 = srcv[k4];
        vbuf[4*k4]=v4.x; vbuf[4*k4+1]=v4.y; vbuf[4*k4+2]=v4.z; vbuf[4*k4+3]=v4.w;
      }
    }
  } else {
    #pragma unroll
    for (int k=0;k<16;k++) vbuf[k]=0.f;
  }
  #pragma unroll
  for (int k=0;k<16;k++) A->v[(p-p0)*33 + dbase + k] = vbuf[k];
  __syncthreads();
  float m = (tid < 128) ? A->sc[tid] : -1e30f;
  #pragma unroll
  for (int o=32;o;o>>=1) m = fmaxf(m, __shfl_xor(m, o));
  if ((tid&63)==0) A->red[tid>>6] = m;
  __syncthreads();
  m = fmaxf(fmaxf(A->red[0],A->red[1]), fmaxf(A->red[2],A->red[3]));
  __syncthreads();
  float e = 0.f;
  if (tid < 128){
    int pp = p0 + tid;
    e = (pp < nlen) ? expf(A->sc[tid] - m) : 0.f;
    A->e[tid] = e;
  }
  float ssum = e;
  #pragma unroll
  for (int o=32;o;o>>=1) ssum += __shfl_xor(ssum, o);
  if ((tid&63)==0) A->red[tid>>6] = ssum;
  __syncthreads();
  ssum = A->red[0]+A->red[1]+A->red[2]+A->red[3];
  __syncthreads();
  const int d = tid & 31, grp = tid >> 5;
  float oacc = 0.f;
  #pragma unroll
  for (int q2=0;q2<16;q2++){ int pp = (grp<<4) + q2; oacc += A->e[pp] * A->v[pp*33 + d]; }
  A->red[tid] = oacc;
  __syncthreads();
  float* rec = &wpart[(size_t)(h*16 + c)*34];
  if (tid < 32){
    float o8 = 0.f;
    #pragma unroll
    for (int g=0; g<8; g++) o8 += A->red[tid + (g<<5)];
    gst(&rec[2+tid], o8);
  }
  if (tid == 0){ gst(&rec[0], m); gst(&rec[1], ssum); }
  done_add(&C[HEAD_C(h)], tid);
}

__global__ __launch_bounds__(NT, 1)
void t2s_decode(const int* __restrict__ LT, const int* __restrict__ PI, const int* __restrict__ CL,
                const float* __restrict__ KC, const float* __restrict__ VC,
                const float* __restrict__ EMB, const float* __restrict__ PE,
                const float* __restrict__ XSc, const float* __restrict__ ALp,
                const float* __restrict__ QKVW, const float* __restrict__ QKVB,
                const float* __restrict__ OUTW, const float* __restrict__ OUTB,
                const float* __restrict__ NW1, const float* __restrict__ NB1,
                const float* __restrict__ NW2, const float* __restrict__ NB2,
                const float* __restrict__ W1, const float* __restrict__ B1,
                const float* __restrict__ W2, const float* __restrict__ B2,
                const float* __restrict__ PW, const float* __restrict__ PB,
                float* __restrict__ OUT, float* __restrict__ WS)
{
  __shared__ Lds L;
  const int b = blockIdx.x, tid = threadIdx.x;

  int* C = (int*)WS;            // 130 counters/flags x 64B (zeroed by memset)
  float* F    = WS + 2112;
  float* wx   = F;              // [512]   layer input x (LN2 out / xy)
  float* wx1  = F + 512;        // [512]   LN1 output
  float* wqkv = F + 1024;       // [1536]  q(pre-scaled)|k|v
  float* wop  = F + 2560;       // [16*512] out-proj K-slice partials
  float* wh   = F + 10752;      // [2048]  ff1 output (relu'd)
  float* wpart= F + 12800;      // [256*34] attn partials (m,S,o[32])
  float* wf2  = F + 21504;      // [8*512]  ff2 partials

  float* KO = OUT + 1029;
  float* VO = KO + (size_t)NL*CAPCTX*HIDDEN;

  const int token = LT[0], posi = PI[0], clen = CL[0], nlen = clen + 1;

  float pfA[32];          // qkv W slab          (b<96)
  float pfQb = 0.f;       // qkv bias            (b<96)
  float pfLNb[2], pfLNw[2], pfLNn[2];   // B2/NW2/NB2 for next build_xn (b<96)
  float pfF1[32];         // ff1 W slab          (96..223)
  float pfOB[2], pfW1n[2], pfB1n[2], pfB1f; // OUTB/NW1/NB1/B1 (96..223)
  float pfF2[16];         // ff2 W slab          (all)
  float pfO[64];          // out-proj slab       (masters 224..239)

  // initial prefetch (layer 0)
  if (b < 96){
    const float* Wq = QKVW + (size_t)(tid>>4)*H3 + (b<<4) + (tid&15);
    #pragma unroll
    for (int k=0;k<32;k++) pfA[k] = Wq[(size_t)k*16*H3];
    pfQb = QKVB[(b<<4) + (tid&15)];
    PIN();
  }

  for (int l=0; l<NL; l++){
    // ---- masters prefetch out-proj slab ------------------------------------
    if (b >= 224 && b < 240){
      const int h = b - 224;
      const float* Wo = OUTW + (size_t)l*HIDDEN*HIDDEN + (size_t)(h*HD)*HIDDEN + tid;
      #pragma unroll
      for (int d=0;d<32;d++){ pfO[d] = Wo[(size_t)d*HIDDEN]; pfO[32+d] = Wo[(size_t)d*HIDDEN + 256]; }
      PIN();
    }

    // ---- role A: qkv GEMV (blocks 0..95) -----------------------------------
    if (b < 96){
      if (l == 0){
        float xs = XSc[0], al = ALp[0];
        for (int i=tid;i<HIDDEN;i+=NT){
          float v = EMB[(size_t)token*HIDDEN+i]*xs + al*PE[(size_t)posi*HIDDEN+i];
          L.g.xn[i] = v;
          if (b == 0) gst(&wx[i], v);
        }
        __syncthreads();
      } else {
        waitgeN(C + FF2_C(0), 8, 32*l);
        // build LN2(x1 + b2 + sum ff2) from prefetched LN params
        float s1=0.f, s2=0.f;
        #pragma unroll
        for (int r=0;r<2;r++){
          int i = tid + r*NT;
          float t = gld(&wx1[i]) + pfLNb[r];
          #pragma unroll
          for (int rg=0; rg<8; rg++) t += gld(&wf2[rg*HIDDEN + i]);
          L.g.xload[i] = t; s1 += t; s2 += t*t;
        }
        bsum2(s1, s2, L.g.r8, tid);
        float mu = s1*(1.f/HIDDEN), rstd = rsqrtf(s2*(1.f/HIDDEN)-mu*mu+EPSLN);
        #pragma unroll
        for (int r=0;r<2;r++){
          int i = tid + r*NT;
          float v = (L.g.xload[i]-mu)*rstd*pfLNw[r] + pfLNn[r];
          L.g.xn[i] = v;
          if (b == 0) gst(&wx[i], v);
        }
        __syncthreads();
      }
      float dsum = dotred<32>(pfA, L.g.xn, L.g.red, tid);
      if (tid < 16){
        int j = (b<<4) + tid;
        float val = dsum + pfQb;
        if (j < HIDDEN) val *= ISQ;
        gst(&wqkv[j], val);
        if (j >= HIDDEN && j < 2*HIDDEN)  KO[((size_t)l*CAPCTX + clen)*HIDDEN + (j-HIDDEN)]   = val;
        else if (j >= 2*HIDDEN)           VO[((size_t)l*CAPCTX + clen)*HIDDEN + (j-2*HIDDEN)] = val;
      }
      __syncthreads();                       // drain wqkv + KV-row stores
      if (tid == 0) ist(&C[QFLAG(b)], l+1);  // per-block flag
    }

    // ---- attention tasks (chunk-major: task t -> c=t>>4, h=t&15) -----------
    if (b < 224) attn_task(l, b & 15, b >> 4, clen, nlen, KC, VC, wqkv, wpart, C, &L.a, tid);
    if (b < 32)  attn_task(l, b & 15, 14 + (b >> 4), clen, nlen, KC, VC, wqkv, wpart, C, &L.a, tid);

    // ---- prefetches (soak during upcoming waits) ---------------------------
    if (b < 96){
      if (l < NL-1){
        const float* Wq = QKVW + (size_t)(l+1)*HIDDEN*H3 + (size_t)(tid>>4)*H3 + (b<<4) + (tid&15);
        #pragma unroll
        for (int k=0;k<32;k++) pfA[k] = Wq[(size_t)k*16*H3];
        pfQb = QKVB[(size_t)(l+1)*H3 + (b<<4) + (tid&15)];
      }
      #pragma unroll
      for (int r=0;r<2;r++){
        int i = tid + r*NT;
        pfLNb[r] = B2[(size_t)l*HIDDEN + i];
        pfLNw[r] = NW2[(size_t)l*HIDDEN + i];
        pfLNn[r] = NB2[(size_t)l*HIDDEN + i];
      }
    }
    if (b >= 96 && b < 224){
      const int j0 = (b-96) << 4;
      const float* W1p = W1 + (size_t)l*HIDDEN*FFD + (size_t)(tid>>4)*FFD + j0 + (tid&15);
      #pragma unroll
      for (int k=0;k<32;k++) pfF1[k] = W1p[(size_t)k*16*FFD];
      #pragma unroll
      for (int r=0;r<2;r++){
        int i = tid + r*NT;
        pfOB[r]  = OUTB[(size_t)l*HIDDEN + i];
        pfW1n[r] = NW1[(size_t)l*HIDDEN + i];
        pfB1n[r] = NB1[(size_t)l*HIDDEN + i];
      }
      pfB1f = B1[(size_t)l*FFD + j0 + (tid&15)];
    }
    {
      const int rg = b & 7, cg = b >> 3;
      const float* W2p = W2 + (size_t)l*FFD*HIDDEN + (size_t)(rg*256 + (tid>>4))*HIDDEN + (cg<<4) + (tid&15);
      #pragma unroll
      for (int k=0;k<16;k++) pfF2[k] = W2p[(size_t)k*16*HIDDEN];
    }
    PIN();

    // ---- masters: combine + out-proj K-slice (blocks 224..239) -------------
    if (b >= 224 && b < 240){
      const int h = b - 224;
      waitge1(&C[HEAD_C(h)], 16*(l+1));
      const float* prt = &wpart[(size_t)(h*16)*34];
      if (tid < 16){ L.c.m16[tid] = gld(&prt[(size_t)tid*34]); L.c.s16[tid] = gld(&prt[(size_t)tid*34+1]); }
      __syncthreads();
      float M = L.c.m16[0];
      #pragma unroll
      for (int c=1;c<16;c++) M = fmaxf(M, L.c.m16[c]);
      float S = 0.f;
      #pragma unroll
      for (int c=0;c<16;c++) S += L.c.s16[c]*expf(L.c.m16[c]-M);
      if (tid < 32){
        float o = 0.f;
        #pragma unroll
        for (int c=0;c<16;c++) o += expf(L.c.m16[c]-M)*gld(&prt[(size_t)c*34+2+tid]);
        L.c.o32[tid] = o / S;
      }
      __syncthreads();
      float a0=0.f, a1=0.f;
      #pragma unroll
      for (int d=0; d<32; d++){ a0 += L.c.o32[d]*pfO[d]; a1 += L.c.o32[d]*pfO[32+d]; }
      gst(&wop[h*HIDDEN + tid], a0);
      gst(&wop[h*HIDDEN + 256 + tid], a1);
      done_add(&C[OP_C], tid);
    }

    // ---- role D: residual + LN1 + ff1 (blocks 96..223) ---------------------
    if (b >= 96 && b < 224){
      waitge1(&C[OP_C], 16*(l+1));
      float s1=0.f, s2=0.f;
      #pragma unroll
      for (int r=0;r<2;r++){
        int i = tid + r*NT;
        float t = gld(&wx[i]) + pfOB[r];
        #pragma unroll
        for (int h2=0;h2<16;h2++) t += gld(&wop[h2*HIDDEN+i]);
        L.g.xload[i]=t; s1+=t; s2+=t*t;
      }
      bsum2(s1,s2,L.g.r8,tid);
      float mu = s1*(1.f/HIDDEN), rstd = rsqrtf(s2*(1.f/HIDDEN)-mu*mu+EPSLN);
      #pragma unroll
      for (int r=0;r<2;r++){
        int i = tid + r*NT;
        float xx = (L.g.xload[i]-mu)*rstd*pfW1n[r] + pfB1n[r];
        L.g.xn[i]=xx;
        if (b==96) gst(&wx1[i], xx);
      }
      __syncthreads();
      float dsum = dotred<32>(pfF1, L.g.xn, L.g.red, tid);
      if (tid < 16){
        int j = ((b-96)<<4) + tid;
        gst(&wh[j], fmaxf(dsum + pfB1f, 0.f));
      }
      done_add(&C[FF1_C((b-96)>>4)], tid);
    }

    // ---- role E: ff2 partials (all 256: rg=b&7, cg=b>>3) -------------------
    {
      const int rg = b & 7, cg = b >> 3;
      waitge1(&C[FF1_C(rg)], 16*(l+1));
      L.g.xn[tid] = gld(&wh[rg*256 + tid]);
      __syncthreads();
      float dsum = dotred<16>(pfF2, L.g.xn, L.g.red, tid);
      if (tid < 16) gst(&wf2[rg*HIDDEN + (cg<<4) + tid], dsum);
      done_add(&C[FF2_C(rg)], tid);
    }

    // ---- KV copy + tail zero (blocks 96..223, 240..255) at loop end --------
    // overlaps next layer's qkv stage for these blocks
    if ((b >= 96 && b < 224) || b >= 240){
      const int idx = (b < 224) ? (b - 96) : (128 + (b - 240));   // 0..143
      const int t7 = tid & 127, halfr = tid >> 7;
      const float4 z4 = make_float4(0.f,0.f,0.f,0.f);
      for (int r0 = idx*2; r0 < 4096; r0 += 288){
        int r = r0 + halfr;
        int p = r & 2047, isv = r >> 11;
        if (p != clen){
          float4* dst = (float4*)((isv ? VO : KO) + ((size_t)l*CAPCTX + p)*HIDDEN);
          if (p < clen){
            const float4* src = (const float4*)((isv ? VC : KC) + ((size_t)l*CAPCTX + p)*HIDDEN);
            dst[t7] = src[t7];
          } else {
            dst[t7] = z4;
          }
        }
      }
    }
  }

  // ---- pred logits (blocks 0..64) ------------------------------------------
  if (b < 65){
    const int v0 = b << 4;
    const int nrows = (b == 64) ? 1 : 16;
    const int rr = tid >> 4, s2l = tid & 15;
    float pfP[32]; float pfPb = 0.f;
    if (rr < nrows){
      const float* row = PW + (size_t)(v0+rr)*HIDDEN;
      #pragma unroll
      for (int mm=0; mm<32; mm++) pfP[mm] = row[s2l + (mm<<4)];
      pfPb = PB[v0+rr];
    }
    PIN();
    waitgeN(C + FF2_C(0), 8, 32*NL);
    // final LN2 (params prefetched at l=23)
    float s1=0.f, s2=0.f;
    #pragma unroll
    for (int r=0;r<2;r++){
      int i = tid + r*NT;
      float t = gld(&wx1[i]) + pfLNb[r];
      #pragma unroll
      for (int rg=0; rg<8; rg++) t += gld(&wf2[rg*HIDDEN + i]);
      L.g.xload[i] = t; s1 += t; s2 += t*t;
    }
    bsum2(s1, s2, L.g.r8, tid);
    float mu = s1*(1.f/HIDDEN), rstd = rsqrtf(s2*(1.f/HIDDEN)-mu*mu+EPSLN);
    #pragma unroll
    for (int r=0;r<2;r++){
      int i = tid + r*NT;
      L.g.xn[i] = (L.g.xload[i]-mu)*rstd*pfLNw[r] + pfLNn[r];
    }
    __syncthreads();
    if (rr < nrows){
      float acc = 0.f;
      #pragma unroll
      for (int mm=0; mm<32; mm++) acc += L.g.xn[s2l + (mm<<4)] * pfP[mm];
      #pragma unroll
      for (int o=1;o<16;o<<=1) acc += __shfl_xor(acc, o);
      if (s2l == 0) gst(&OUT[v0+rr], acc + pfPb);
    }
    done_add(&C[PRED_C], tid);
  }

  // ---- final: argmax + scalars (block 0) -----------------------------------
  if (b == 0){
    waitge1(&C[PRED_C], 65);
    float bv = -3.0e38f; int bi = 0;
    for (int v=tid; v<NVOCAB; v+=NT){
      float x = gld(&OUT[v]);
      if (x > bv){ bv = x; bi = v; }
    }
    L.g.xload[tid] = bv;
    ((int*)L.g.xn)[tid] = bi;
    __syncthreads();
    for (int step=128; step; step>>=1){
      if (tid < step){
        float ov2 = L.g.xload[tid+step]; int oi = ((int*)L.g.xn)[tid+step];
        float mv  = L.g.xload[tid];      int mi = ((int*)L.g.xn)[tid];
        if (ov2 > mv || (ov2 == mv && oi < mi)){ L.g.xload[tid]=ov2; ((int*)L.g.xn)[tid]=oi; }
      }
      __syncthreads();
    }
    if (tid == 0){
      int bi0 = ((int*)L.g.xn)[0];
      OUT[NVOCAB]   = (float)bi0;
      OUT[NVOCAB+1] = (bi0 == 1024) ? 1.f : 0.f;
      OUT[NVOCAB+2] = (float)nlen;
      OUT[NVOCAB+3] = (float)(posi + 1);
    }
  }
}

extern "C" void kernel_launch(void* const* d_in, const int* in_sizes, int n_in,
                              void* d_out, int out_size, void* d_ws, size_t ws_size,
                              hipStream_t stream) {
  (void)in_sizes; (void)n_in; (void)out_size; (void)ws_size;
  // zero flags/counters every call (replay-safe)
  hipMemsetAsync(d_ws, 0, 8448, stream);
  t2s_decode<<<GRID, NT, 0, stream>>>(
    (const int*)d_in[0], (const int*)d_in[1], (const int*)d_in[2],
    (const float*)d_in[3], (const float*)d_in[4],
    (const float*)d_in[5], (const float*)d_in[6],
    (const float*)d_in[7], (const float*)d_in[8],
    (const float*)d_in[9], (const float*)d_in[10],
    (const float*)d_in[11], (const float*)d_in[12],
    (const float*)d_in[13], (const float*)d_in[14],
    (const float*)d_in[15], (const float*)d_in[16],
    (const float*)d_in[17], (const float*)d_in[18],
    (const float*)d_in[19], (const float*)d_in[20],
    (const float*)d_in[21], (const float*)d_in[22],
    (float*)d_out, (float*)d_ws);
}

// Round 5
// 459.495 us; speedup vs baseline: 5.6574x; 1.5550x over previous
//
#include <hip/hip_runtime.h>
#include <math.h>

#define NL     24
#define HIDDEN 512
#define H3     1536
#define HD     32
#define CAPCTX 2048
#define FFD    2048
#define NVOCAB 1025
#define GRID   256
#define NT     256
#define EPSLN  1e-5f
#define ISQ    0.17677669529663687f  /* 1/sqrt(32) */

// ---- agent-scope (LLC-coherent, relaxed) helpers ---------------------------
__device__ __forceinline__ float gld(const float* p){ return __hip_atomic_load(p, __ATOMIC_RELAXED, __HIP_MEMORY_SCOPE_AGENT); }
__device__ __forceinline__ void  gst(float* p, float v){ __hip_atomic_store(p, v, __ATOMIC_RELAXED, __HIP_MEMORY_SCOPE_AGENT); }
__device__ __forceinline__ int   ild(const int* p){ return __hip_atomic_load(p, __ATOMIC_RELAXED, __HIP_MEMORY_SCOPE_AGENT); }
__device__ __forceinline__ void  ist(int* p, int v){ __hip_atomic_store(p, v, __ATOMIC_RELAXED, __HIP_MEMORY_SCOPE_AGENT); }

__device__ __forceinline__ void done_add(int* ctr, int tid){
  __syncthreads();   // drains vmcnt(0): all block stores/atomics at LLC first
  if (tid == 0) __hip_atomic_fetch_add(ctr, 1, __ATOMIC_RELAXED, __HIP_MEMORY_SCOPE_AGENT);
}
__device__ __forceinline__ void waitge1(const int* c, int tgt){
  if (threadIdx.x == 0){
    int g = 0;
    while (__hip_atomic_load(c, __ATOMIC_RELAXED, __HIP_MEMORY_SCOPE_AGENT) < tgt){
      if (++g > (1<<25)) break;   // safety: never hang the harness
    }
  }
  __syncthreads();
}
__device__ __forceinline__ void waitgeN(const int* base, int n, int tgt){
  if ((int)threadIdx.x < n){
    const int* c = base + threadIdx.x*16;
    int g = 0;
    while (__hip_atomic_load(c, __ATOMIC_RELAXED, __HIP_MEMORY_SCOPE_AGENT) < tgt){
      if (++g > (1<<25)) break;
    }
  }
  __syncthreads();
}
#define PIN() asm volatile("" ::: "memory")

// counter map (each on its own 64B line)
#define QFLAG(b)  ((b)*16)        // 96 per-block qkv flags (value = l+1)
#define HEAD_C(h) ((96+(h))*16)   // 16 head counters (nch adds/layer)
#define OP_C      (112*16)        // out-proj done (16 adds/layer)
#define FF1G(g)   ((113+(g))*16)  // 8 groups (16 adds/layer)
#define PRED_C    (121*16)        // 65 adds

struct LdsG { float xload[HIDDEN]; float xn[HIDDEN]; float red[16*17]; float r8[8]; float h16[16]; };
struct LdsA { float q[HD]; float sc[128]; float e[128]; float v[128*33]; float red[NT]; };
struct LdsC { float m16[16]; float s16[16]; float o32[32]; };
union  Lds  { LdsG g; LdsA a; LdsC c; };

__device__ __forceinline__ void bsum2(float &a, float &bb, float* lds8, int tid){
  #pragma unroll
  for (int o=32;o;o>>=1){ a += __shfl_down(a,o); bb += __shfl_down(bb,o); }
  __syncthreads();
  if ((tid&63)==0){ int w=tid>>6; lds8[w]=a; lds8[4+w]=bb; }
  __syncthreads();
  a  = lds8[0]+lds8[1]+lds8[2]+lds8[3];
  bb = lds8[4]+lds8[5]+lds8[6]+lds8[7];
  __syncthreads();
}

template<int K>
__device__ __forceinline__ float dotred(const float* w, const float* xn, float* red, int tid){
  const int c = tid & 15, s = tid >> 4;
  float a = 0.f;
  #pragma unroll
  for (int k=0;k<K;k++) a += xn[s + 16*k] * w[k];
  red[s*17 + c] = a;
  __syncthreads();
  float d = 0.f;
  if (s == 0){
    #pragma unroll
    for (int k=0;k<16;k++) d += red[k*17 + c];
  }
  __syncthreads();
  return d;
}

// KV copy share (144 sharers: idx 0..143), rows p!=clen
__device__ __forceinline__ void kvcopy(int idx, int l, int clen,
    const float* __restrict__ KC, const float* __restrict__ VC,
    float* KO, float* VO, int tid){
  const int t7 = tid & 127, halfr = tid >> 7;
  const float4 z4 = make_float4(0.f,0.f,0.f,0.f);
  for (int r0 = idx*2; r0 < 4096; r0 += 288){
    int r = r0 + halfr;
    int p = r & 2047, isv = r >> 11;
    if (p != clen){
      float4* dst = (float4*)((isv ? VO : KO) + ((size_t)l*CAPCTX + p)*HIDDEN);
      if (p < clen){
        const float4* src = (const float4*)((isv ? VC : KC) + ((size_t)l*CAPCTX + p)*HIDDEN);
        dst[t7] = src[t7];
      } else {
        dst[t7] = z4;
      }
    }
  }
}

__global__ __launch_bounds__(NT, 1)
void t2s_decode(const int* __restrict__ LT, const int* __restrict__ PI, const int* __restrict__ CL,
                const float* __restrict__ KC, const float* __restrict__ VC,
                const float* __restrict__ EMB, const float* __restrict__ PE,
                const float* __restrict__ XSc, const float* __restrict__ ALp,
                const float* __restrict__ QKVW, const float* __restrict__ QKVB,
                const float* __restrict__ OUTW, const float* __restrict__ OUTB,
                const float* __restrict__ NW1, const float* __restrict__ NB1,
                const float* __restrict__ NW2, const float* __restrict__ NB2,
                const float* __restrict__ W1, const float* __restrict__ B1,
                const float* __restrict__ W2, const float* __restrict__ B2,
                const float* __restrict__ PW, const float* __restrict__ PB,
                float* __restrict__ OUT, float* __restrict__ WS)
{
  __shared__ Lds L;
  const int b = blockIdx.x, tid = threadIdx.x;

  int* C = (int*)WS;              // 122 lines x 64B (zeroed by memset)
  float* F      = WS + 2048;
  float* wopsum = F;              // [2][512]  out-proj atomic accumulators
  float* wf2    = F + 1024;       // [2][8][512] ff2 atomic accumulators
  float* wx     = F + 9216;       // [512] layer input x
  float* wx1    = F + 9728;       // [512] LN1 output
  float* wqkv   = F + 10240;      // [1536] q(pre-scaled)|k|v
  float* wpart  = F + 11776;      // [256*34] attn partials (m,S,o[32])

  float* KO = OUT + 1029;
  float* VO = KO + (size_t)NL*CAPCTX*HIDDEN;

  const int token = LT[0], posi = PI[0], clen = CL[0], nlen = clen + 1;
  const int nch = (nlen + 127) >> 7;     // valid 128-pos chunks (<=8 here)

  float pfA[32];   float pfQb = 0.f;                 // qkv W slab + bias (b<96)
  float pfLNb[2], pfLNw[2], pfLNn[2];                // B2/NW2/NB2 (b<96)
  float pfF1[32];                                    // ff1 W slab (96..223)
  float pfOB[2], pfW1n[2], pfB1n[2], pfB1f = 0.f;    // OUTB/NW1/NB1/B1 (96..223)
  float pfF2[32];                                    // ff2 W tile (96..223)
  float pfO[64];                                     // out-proj slab (240..255)

  // initial qkv prefetch (layer 0)
  if (b < 96){
    const float* Wq = QKVW + (size_t)(tid>>4)*H3 + (b<<4) + (tid&15);
    #pragma unroll
    for (int k=0;k<32;k++) pfA[k] = Wq[(size_t)k*16*H3];
    pfQb = QKVB[(b<<4) + (tid&15)];
    PIN();
  }

  for (int l=0; l<NL; l++){
    const int par = l & 1;

    // ================= attention blocks 128..255 =============================
    if (b >= 128){
      const int t = b - 128, h = t & 15, ci = t >> 4;
      const bool do_attn = (ci < nch);
      const int pl = tid >> 1, half = tid & 1, dbase = half << 4;
      const int p = (ci << 7) + pl;
      const bool valid = do_attn && (p < nlen);
      const bool isnew = valid && (p == clen);
      float kbuf[16], vbuf[16];

      // masters: issue out-proj slab loads first
      if (b >= 240){
        const float* Wo = OUTW + (size_t)l*HIDDEN*HIDDEN + (size_t)((b-240)*HD)*HIDDEN + tid;
        #pragma unroll
        for (int d=0;d<32;d++){ pfO[d] = Wo[(size_t)d*HIDDEN]; pfO[32+d] = Wo[(size_t)d*HIDDEN + 256]; }
      }
      // K/V register prefetch BEFORE the q-wait (hides HBM latency)
      if (valid && !isnew){
        const size_t rowoff = ((size_t)l*CAPCTX + p)*HIDDEN + h*HD + dbase;
        const float4* sk = (const float4*)(KC + rowoff);
        const float4* sv = (const float4*)(VC + rowoff);
        #pragma unroll
        for (int k4=0;k4<4;k4++){
          float4 a = sk[k4];
          kbuf[4*k4]=a.x; kbuf[4*k4+1]=a.y; kbuf[4*k4+2]=a.z; kbuf[4*k4+3]=a.w;
          float4 c = sv[k4];
          vbuf[4*k4]=c.x; vbuf[4*k4+1]=c.y; vbuf[4*k4+2]=c.z; vbuf[4*k4+3]=c.w;
        }
      }
      PIN();

      if (do_attn){
        // wait only the 6 qkv producer blocks for head h
        if (tid < 6){
          int pb = (tid>>1)*32 + 2*h + (tid&1);
          const int* f = C + QFLAG(pb);
          int g = 0;
          while (ild(f) < l+1){ if (++g > (1<<25)) break; }
        }
        __syncthreads();
        if (tid < HD) L.a.q[tid] = gld(&wqkv[h*HD + tid]);
        __syncthreads();
        float dotp = 0.f;
        if (valid){
          if (isnew){
            #pragma unroll
            for (int k=0;k<16;k++){
              kbuf[k] = gld(&wqkv[HIDDEN   + h*HD + dbase + k]);
              vbuf[k] = gld(&wqkv[2*HIDDEN + h*HD + dbase + k]);
            }
          }
          #pragma unroll
          for (int k=0;k<16;k++) dotp += kbuf[k] * L.a.q[dbase+k];
        } else {
          #pragma unroll
          for (int k=0;k<16;k++) vbuf[k] = 0.f;
        }
        dotp += __shfl_xor(dotp, 1);
        if (half == 0) L.a.sc[pl] = valid ? dotp : -1e30f;
        #pragma unroll
        for (int k=0;k<16;k++) L.a.v[pl*33 + dbase + k] = vbuf[k];
        __syncthreads();
        float m = (tid < 128) ? L.a.sc[tid] : -1e30f;
        #pragma unroll
        for (int o=32;o;o>>=1) m = fmaxf(m, __shfl_xor(m, o));
        if ((tid&63)==0) L.a.red[tid>>6] = m;
        __syncthreads();
        m = fmaxf(fmaxf(L.a.red[0],L.a.red[1]), fmaxf(L.a.red[2],L.a.red[3]));
        __syncthreads();
        float e = 0.f;
        if (tid < 128){
          int pp = (ci<<7) + tid;
          e = (pp < nlen) ? expf(L.a.sc[tid] - m) : 0.f;
          L.a.e[tid] = e;
        }
        float ssum = e;
        #pragma unroll
        for (int o=32;o;o>>=1) ssum += __shfl_xor(ssum, o);
        if ((tid&63)==0) L.a.red[tid>>6] = ssum;
        __syncthreads();
        ssum = L.a.red[0]+L.a.red[1]+L.a.red[2]+L.a.red[3];
        __syncthreads();
        const int d = tid & 31, grp = tid >> 5;
        float oacc = 0.f;
        #pragma unroll
        for (int q2=0;q2<16;q2++){ int pp = (grp<<4) + q2; oacc += L.a.e[pp] * L.a.v[pp*33 + d]; }
        L.a.red[tid] = oacc;
        __syncthreads();
        float* rec = &wpart[(size_t)(h*16 + ci)*34];
        if (tid < 32){
          float o8 = 0.f;
          #pragma unroll
          for (int g=0; g<8; g++) o8 += L.a.red[tid + (g<<5)];
          gst(&rec[2+tid], o8);
        }
        if (tid == 0){ gst(&rec[0], m); gst(&rec[1], ssum); }
        done_add(&C[HEAD_C(h)], tid);
      }
    }

    // ================= masters: combine + out-proj (240..255) ===============
    if (b >= 240){
      const int h = b - 240;
      waitge1(&C[HEAD_C(h)], nch*(l+1));
      if (tid < 32) gst(&wopsum[(par^1)*HIDDEN + h*32 + tid], 0.f);  // zero next-layer buf
      const float* rec0 = &wpart[(size_t)(h*16)*34];
      if (tid < nch){ L.c.m16[tid] = gld(&rec0[(size_t)tid*34]); L.c.s16[tid] = gld(&rec0[(size_t)tid*34+1]); }
      __syncthreads();
      float M = -3.0e38f;
      for (int c=0;c<nch;c++) M = fmaxf(M, L.c.m16[c]);
      float S = 0.f;
      for (int c=0;c<nch;c++) S += L.c.s16[c]*expf(L.c.m16[c]-M);
      if (tid < 32){
        float o = 0.f;
        for (int c=0;c<nch;c++) o += expf(L.c.m16[c]-M)*gld(&rec0[(size_t)c*34+2+tid]);
        L.c.o32[tid] = o / S;
      }
      __syncthreads();
      float a0=0.f, a1=0.f;
      #pragma unroll
      for (int d=0; d<32; d++){ a0 += L.c.o32[d]*pfO[d]; a1 += L.c.o32[d]*pfO[32+d]; }
      unsafeAtomicAdd(&wopsum[par*HIDDEN + tid], a0);
      unsafeAtomicAdd(&wopsum[par*HIDDEN + 256 + tid], a1);
      done_add(&C[OP_C], tid);
    }

    // ---- copy: blocks 224..239 after their attn chunk ----------------------
    if (b >= 224 && b < 240) kvcopy(128 + (b-224), l, clen, KC, VC, KO, VO, tid);

    // ================= ff1 + fused ff2 (blocks 96..223) =====================
    if (b >= 96 && b < 224){
      const int f = b - 96, j0 = f << 4, rg = f >> 4;
      if (b < 128) kvcopy(b, l, clen, KC, VC, KO, VO, tid);   // 96..127 copy early
      // prefetch W1 slab, W2 tile, layer params
      {
        const float* W1p = W1 + (size_t)l*HIDDEN*FFD + (size_t)(tid>>4)*FFD + j0 + (tid&15);
        #pragma unroll
        for (int k=0;k<32;k++) pfF1[k] = W1p[(size_t)k*16*FFD];
        const float* W2p = W2 + (size_t)l*FFD*HIDDEN + (size_t)j0*HIDDEN + tid;
        #pragma unroll
        for (int c=0;c<16;c++){ pfF2[c] = W2p[(size_t)c*HIDDEN]; pfF2[16+c] = W2p[(size_t)c*HIDDEN + 256]; }
        #pragma unroll
        for (int r=0;r<2;r++){
          int i = tid + r*NT;
          pfOB[r]  = OUTB[(size_t)l*HIDDEN + i];
          pfW1n[r] = NW1[(size_t)l*HIDDEN + i];
          pfB1n[r] = NB1[(size_t)l*HIDDEN + i];
        }
        pfB1f = B1[(size_t)l*FFD + j0 + (tid&15)];
        PIN();
      }
      waitge1(&C[OP_C], 16*(l+1));
      if (tid < 32) gst(&wf2[(par^1)*4096 + f*32 + tid], 0.f);  // zero next-layer buf
      float s1=0.f, s2=0.f;
      #pragma unroll
      for (int r=0;r<2;r++){
        int i = tid + r*NT;
        float tt = gld(&wx[i]) + pfOB[r] + gld(&wopsum[par*HIDDEN + i]);
        L.g.xload[i]=tt; s1+=tt; s2+=tt*tt;
      }
      bsum2(s1,s2,L.g.r8,tid);
      float mu = s1*(1.f/HIDDEN), rstd = rsqrtf(s2*(1.f/HIDDEN)-mu*mu+EPSLN);
      #pragma unroll
      for (int r=0;r<2;r++){
        int i = tid + r*NT;
        float xx = (L.g.xload[i]-mu)*rstd*pfW1n[r] + pfB1n[r];
        L.g.xn[i]=xx;
        if (b==96) gst(&wx1[i], xx);
      }
      __syncthreads();
      float dsum = dotred<32>(pfF1, L.g.xn, L.g.red, tid);
      if (tid < 16) L.g.h16[tid] = fmaxf(dsum + pfB1f, 0.f);
      __syncthreads();
      float a0=0.f, a1=0.f;
      #pragma unroll
      for (int c=0;c<16;c++){ float hv = L.g.h16[c]; a0 += hv*pfF2[c]; a1 += hv*pfF2[16+c]; }
      unsafeAtomicAdd(&wf2[par*4096 + rg*512 + tid], a0);
      unsafeAtomicAdd(&wf2[par*4096 + rg*512 + 256 + tid], a1);
      done_add(&C[FF1G(rg)], tid);
    }

    // ================= qkv (blocks 0..95) ===================================
    if (b < 96){
      if (l == 0){
        float xs = XSc[0], al = ALp[0];
        for (int i=tid;i<HIDDEN;i+=NT){
          float v = EMB[(size_t)token*HIDDEN+i]*xs + al*PE[(size_t)posi*HIDDEN+i];
          L.g.xn[i] = v;
          if (b == 0) gst(&wx[i], v);
        }
        __syncthreads();
      } else {
        waitgeN(C + FF1G(0), 8, 16*l);
        float s1=0.f, s2=0.f;
        const float* f2p = wf2 + (par^1)*4096;   // layer l-1's accumulators
        #pragma unroll
        for (int r=0;r<2;r++){
          int i = tid + r*NT;
          float tt = gld(&wx1[i]) + pfLNb[r];
          #pragma unroll
          for (int rg=0; rg<8; rg++) tt += gld(&f2p[rg*512 + i]);
          L.g.xload[i] = tt; s1 += tt; s2 += tt*tt;
        }
        bsum2(s1, s2, L.g.r8, tid);
        float mu = s1*(1.f/HIDDEN), rstd = rsqrtf(s2*(1.f/HIDDEN)-mu*mu+EPSLN);
        #pragma unroll
        for (int r=0;r<2;r++){
          int i = tid + r*NT;
          float v = (L.g.xload[i]-mu)*rstd*pfLNw[r] + pfLNn[r];
          L.g.xn[i] = v;
          if (b == 0) gst(&wx[i], v);
        }
        __syncthreads();
      }
      float dsum = dotred<32>(pfA, L.g.xn, L.g.red, tid);
      if (tid < 16){
        int j = (b<<4) + tid;
        float val = dsum + pfQb;
        if (j < HIDDEN) val *= ISQ;
        gst(&wqkv[j], val);
        if (j >= HIDDEN && j < 2*HIDDEN)  KO[((size_t)l*CAPCTX + clen)*HIDDEN + (j-HIDDEN)]   = val;
        else if (j >= 2*HIDDEN)           VO[((size_t)l*CAPCTX + clen)*HIDDEN + (j-2*HIDDEN)] = val;
      }
      __syncthreads();                        // drain stores
      if (tid == 0) ist(&C[QFLAG(b)], l+1);
      // copy share + next-layer prefetch during the long idle window
      kvcopy(b, l, clen, KC, VC, KO, VO, tid);
      if (l < NL-1){
        const float* Wq = QKVW + (size_t)(l+1)*HIDDEN*H3 + (size_t)(tid>>4)*H3 + (b<<4) + (tid&15);
        #pragma unroll
        for (int k=0;k<32;k++) pfA[k] = Wq[(size_t)k*16*H3];
        pfQb = QKVB[(size_t)(l+1)*H3 + (b<<4) + (tid&15)];
      }
      #pragma unroll
      for (int r=0;r<2;r++){
        int i = tid + r*NT;
        pfLNb[r] = B2[(size_t)l*HIDDEN + i];
        pfLNw[r] = NW2[(size_t)l*HIDDEN + i];
        pfLNn[r] = NB2[(size_t)l*HIDDEN + i];
      }
      PIN();
    }
  }

  // ================= pred logits (blocks 0..64) =============================
  if (b < 65){
    const int v0 = b << 4;
    const int nrows = (b == 64) ? 1 : 16;
    const int rr = tid >> 4, s2l = tid & 15;
    float pfP[32]; float pfPb = 0.f;
    if (rr < nrows){
      const float* row = PW + (size_t)(v0+rr)*HIDDEN;
      #pragma unroll
      for (int mm=0; mm<32; mm++) pfP[mm] = row[s2l + (mm<<4)];
      pfPb = PB[v0+rr];
    }
    PIN();
    waitgeN(C + FF1G(0), 8, 16*NL);
    // final LN2 (params prefetched at l=23); layer-23 ff2 parity = 1
    float s1=0.f, s2=0.f;
    const float* f2p = wf2 + 4096;
    #pragma unroll
    for (int r=0;r<2;r++){
      int i = tid + r*NT;
      float tt = gld(&wx1[i]) + pfLNb[r];
      #pragma unroll
      for (int rg=0; rg<8; rg++) tt += gld(&f2p[rg*512 + i]);
      L.g.xload[i] = tt; s1 += tt; s2 += tt*tt;
    }
    bsum2(s1, s2, L.g.r8, tid);
    float mu = s1*(1.f/HIDDEN), rstd = rsqrtf(s2*(1.f/HIDDEN)-mu*mu+EPSLN);
    #pragma unroll
    for (int r=0;r<2;r++){
      int i = tid + r*NT;
      L.g.xn[i] = (L.g.xload[i]-mu)*rstd*pfLNw[r] + pfLNn[r];
    }
    __syncthreads();
    if (rr < nrows){
      float acc = 0.f;
      #pragma unroll
      for (int mm=0; mm<32; mm++) acc += L.g.xn[s2l + (mm<<4)] * pfP[mm];
      #pragma unroll
      for (int o=1;o<16;o<<=1) acc += __shfl_xor(acc, o);
      if (s2l == 0) gst(&OUT[v0+rr], acc + pfPb);
    }
    done_add(&C[PRED_C], tid);
  }

  // ================= final: argmax + scalars (block 0) ======================
  if (b == 0){
    waitge1(&C[PRED_C], 65);
    float bv = -3.0e38f; int bi = 0;
    for (int v=tid; v<NVOCAB; v+=NT){
      float x = gld(&OUT[v]);
      if (x > bv){ bv = x; bi = v; }
    }
    L.g.xload[tid] = bv;
    ((int*)L.g.xn)[tid] = bi;
    __syncthreads();
    for (int step=128; step; step>>=1){
      if (tid < step){
        float ov2 = L.g.xload[tid+step]; int oi = ((int*)L.g.xn)[tid+step];
        float mv  = L.g.xload[tid];      int mi = ((int*)L.g.xn)[tid];
        if (ov2 > mv || (ov2 == mv && oi < mi)){ L.g.xload[tid]=ov2; ((int*)L.g.xn)[tid]=oi; }
      }
      __syncthreads();
    }
    if (tid == 0){
      int bi0 = ((int*)L.g.xn)[0];
      OUT[NVOCAB]   = (float)bi0;
      OUT[NVOCAB+1] = (bi0 == 1024) ? 1.f : 0.f;
      OUT[NVOCAB+2] = (float)nlen;
      OUT[NVOCAB+3] = (float)(posi + 1);
    }
  }
}

extern "C" void kernel_launch(void* const* d_in, const int* in_sizes, int n_in,
                              void* d_out, int out_size, void* d_ws, size_t ws_size,
                              hipStream_t stream) {
  (void)in_sizes; (void)n_in; (void)out_size; (void)ws_size;
  // zero counters (8192B) + wopsum/wf2 parity accumulators (9216 floats)
  hipMemsetAsync(d_ws, 0, 8192 + 9216*4, stream);
  t2s_decode<<<GRID, NT, 0, stream>>>(
    (const int*)d_in[0], (const int*)d_in[1], (const int*)d_in[2],
    (const float*)d_in[3], (const float*)d_in[4],
    (const float*)d_in[5], (const float*)d_in[6],
    (const float*)d_in[7], (const float*)d_in[8],
    (const float*)d_in[9], (const float*)d_in[10],
    (const float*)d_in[11], (const float*)d_in[12],
    (const float*)d_in[13], (const float*)d_in[14],
    (const float*)d_in[15], (const float*)d_in[16],
    (const float*)d_in[17], (const float*)d_in[18],
    (const float*)d_in[19], (const float*)d_in[20],
    (const float*)d_in[21], (const float*)d_in[22],
    (float*)d_out, (float*)d_ws);
}

// Round 6
// 340.751 us; speedup vs baseline: 7.6289x; 1.3485x over previous
//
#include <hip/hip_runtime.h>
#include <math.h>

#define NL     24
#define HIDDEN 512
#define H3     1536
#define HD     32
#define CAPCTX 2048
#define FFD    2048
#define NVOCAB 1025
#define GRID   256
#define NT     256
#define EPSLN  1e-5f
#define ISQ    0.17677669529663687f  /* 1/sqrt(32) */

// ---- agent-scope (LLC-coherent, relaxed) helpers ---------------------------
__device__ __forceinline__ float gld(const float* p){ return __hip_atomic_load(p, __ATOMIC_RELAXED, __HIP_MEMORY_SCOPE_AGENT); }
__device__ __forceinline__ void  gst(float* p, float v){ __hip_atomic_store(p, v, __ATOMIC_RELAXED, __HIP_MEMORY_SCOPE_AGENT); }
__device__ __forceinline__ int   ild(const int* p){ return __hip_atomic_load(p, __ATOMIC_RELAXED, __HIP_MEMORY_SCOPE_AGENT); }
__device__ __forceinline__ void  ist(int* p, int v){ __hip_atomic_store(p, v, __ATOMIC_RELAXED, __HIP_MEMORY_SCOPE_AGENT); }

__device__ __forceinline__ void done_add(int* ctr, int tid){
  __syncthreads();   // drains vmcnt(0): all block stores/atomics at LLC first
  if (tid == 0) __hip_atomic_fetch_add(ctr, 1, __ATOMIC_RELAXED, __HIP_MEMORY_SCOPE_AGENT);
}
__device__ __forceinline__ void waitge1(const int* c, int tgt){
  if (threadIdx.x == 0){
    int g = 0;
    while (__hip_atomic_load(c, __ATOMIC_RELAXED, __HIP_MEMORY_SCOPE_AGENT) < tgt){
      if (++g > (1<<25)) break;   // safety: never hang the harness
    }
  }
  __syncthreads();
}
__device__ __forceinline__ void waitgeN(const int* base, int n, int tgt){
  if ((int)threadIdx.x < n){
    const int* c = base + threadIdx.x*16;
    int g = 0;
    while (__hip_atomic_load(c, __ATOMIC_RELAXED, __HIP_MEMORY_SCOPE_AGENT) < tgt){
      if (++g > (1<<25)) break;
    }
  }
  __syncthreads();
}
#define PIN() asm volatile("" ::: "memory")

// counter map (each on its own 64B line, int units)
#define KVF(kb)   ((kb)*16)          // 64 kv-block flags (value = l+1)
#define HEADC(h)  ((64+(h))*16)      // 16 head counters (nch adds/layer)
#define FF1G(g)   ((80+(g))*16)      // 8 ffn groups (16 adds/layer)
#define PRED_C    (88*16)            // 65 adds
#define SLINE(par,h) ((90 + (par)*16 + (h))*16)  // fp32 S accumulators

struct LdsF { float xn[HIDDEN]; float red[16*17]; float r8[8]; float s16[16]; float h16[16]; };
struct LdsAt{ float xn[HIDDEN]; float q[HD]; float e[128]; float v[128*33]; float red[288]; float r8[8]; float o32[HD]; };
union  Lds  { LdsF f; LdsAt a; };

__device__ __forceinline__ void bsum2(float &a, float &bb, float* lds8, int tid){
  #pragma unroll
  for (int o=32;o;o>>=1){ a += __shfl_down(a,o); bb += __shfl_down(bb,o); }
  __syncthreads();
  if ((tid&63)==0){ int w=tid>>6; lds8[w]=a; lds8[4+w]=bb; }
  __syncthreads();
  a  = lds8[0]+lds8[1]+lds8[2]+lds8[3];
  bb = lds8[4]+lds8[5]+lds8[6]+lds8[7];
  __syncthreads();
}

template<int K>
__device__ __forceinline__ float dotred(const float* w, const float* xn, float* red, int tid){
  const int c = tid & 15, s = tid >> 4;
  float a = 0.f;
  #pragma unroll
  for (int k=0;k<K;k++) a += xn[s + 16*k] * w[k];
  red[s*17 + c] = a;
  __syncthreads();
  float d = 0.f;
  if (s == 0){
    #pragma unroll
    for (int k=0;k<16;k++) d += red[k*17 + c];
  }
  __syncthreads();
  return d;
}

// KV copy + tail-zero share: sharer idx in [0,T), rows p != clen
__device__ __forceinline__ void kvcopy(int idx, int T, int l, int clen,
    const float* __restrict__ KC, const float* __restrict__ VC,
    float* KO, float* VO, int tid){
  const int t7 = tid & 127, halfr = tid >> 7;
  const float4 z4 = make_float4(0.f,0.f,0.f,0.f);
  for (int r0 = idx*2; r0 < 4096; r0 += 2*T){
    int r = r0 + halfr;
    int p = r & 2047, isv = r >> 11;
    if (p != clen){
      float4* dst = (float4*)((isv ? VO : KO) + ((size_t)l*CAPCTX + p)*HIDDEN);
      if (p < clen){
        const float4* src = (const float4*)((isv ? VC : KC) + ((size_t)l*CAPCTX + p)*HIDDEN);
        dst[t7] = src[t7];
      } else {
        dst[t7] = z4;
      }
    }
  }
}

__global__ __launch_bounds__(NT, 1)
void t2s_decode(const int* __restrict__ LT, const int* __restrict__ PI, const int* __restrict__ CL,
                const float* __restrict__ KC, const float* __restrict__ VC,
                const float* __restrict__ EMB, const float* __restrict__ PE,
                const float* __restrict__ XSc, const float* __restrict__ ALp,
                const float* __restrict__ QKVW, const float* __restrict__ QKVB,
                const float* __restrict__ OUTW, const float* __restrict__ OUTB,
                const float* __restrict__ NW1, const float* __restrict__ NB1,
                const float* __restrict__ NW2, const float* __restrict__ NB2,
                const float* __restrict__ W1, const float* __restrict__ B1,
                const float* __restrict__ W2, const float* __restrict__ B2,
                const float* __restrict__ PW, const float* __restrict__ PB,
                float* __restrict__ OUT, float* __restrict__ WS)
{
  __shared__ Lds L;
  const int b = blockIdx.x, tid = threadIdx.x;

  int* C = (int*)WS;                 // 122 lines x 64B (zeroed by memset)
  float* F   = WS + 2048;            // floats from byte 8192
  float* wop = F;                    // [2][16][512] unnormalized out-proj sums
  float* wf2 = F + 16384;            // [2][8][512]  ff2 partial sums
  float* wx  = F + 24576;            // [512] layer input x (attn input)
  float* wx1 = F + 25088;            // [512] LN1 output
  float* wkv = F + 25600;            // [1024] new-token k|v

  float* KO = OUT + 1029;
  float* VO = KO + (size_t)NL*CAPCTX*HIDDEN;

  const int token = LT[0], posi = PI[0], clen = CL[0], nlen = clen + 1;
  const int nch = (nlen + 127) >> 7;       // <= 8 for this problem
  const int T_copy = 128 + 16*(8 - nch);   // kv-copy sharers

  // ======================= ATTENTION BLOCKS (128..255) ======================
  if (b >= 128){
    const int t = b - 128, h = t & 15, ci = t >> 4;
    const int cstar = clen >> 7;

    if (ci >= nch){
      // idle chunk slot: pure copy duty, no sync
      const int idx = 128 + (ci - nch)*16 + h;
      for (int l=0;l<NL;l++) kvcopy(idx, T_copy, l, clen, KC, VC, KO, VO, tid);
    } else {
      const int c = tid & 31, s5 = tid >> 5;          // q-gemv mapping
      const int pl = tid >> 1, half = tid & 1, dbase = half << 4;
      const int p = (ci << 7) + pl;
      const bool validp = (p < nlen);
      const bool isnew  = validp && (p == clen);

      for (int l=0;l<NL;l++){
        const int par = l & 1;
        // ---- prefetch (issued before the gate; drains during the spin) -----
        float pfQ[64];
        {
          const float* Wq = QKVW + (size_t)l*HIDDEN*H3 + (size_t)s5*H3 + h*HD + c;
          #pragma unroll
          for (int k=0;k<64;k++) pfQ[k] = Wq[(size_t)(k*8)*H3];
        }
        float qb = QKVB[(size_t)l*H3 + h*HD + c];
        float pfO[64];
        {
          const float* Wo = OUTW + (size_t)l*HIDDEN*HIDDEN + (size_t)(h*HD)*HIDDEN + tid;
          #pragma unroll
          for (int d=0;d<32;d++){ pfO[d] = Wo[(size_t)d*HIDDEN]; pfO[32+d] = Wo[(size_t)d*HIDDEN + 256]; }
        }
        float kbuf[16], vbuf[16];
        if (validp && !isnew){
          const size_t rowoff = ((size_t)l*CAPCTX + p)*HIDDEN + h*HD + dbase;
          const float4* sk = (const float4*)(KC + rowoff);
          const float4* sv = (const float4*)(VC + rowoff);
          #pragma unroll
          for (int k4=0;k4<4;k4++){
            float4 a = sk[k4];
            kbuf[4*k4]=a.x; kbuf[4*k4+1]=a.y; kbuf[4*k4+2]=a.z; kbuf[4*k4+3]=a.w;
            float4 cc = sv[k4];
            vbuf[4*k4]=cc.x; vbuf[4*k4+1]=cc.y; vbuf[4*k4+2]=cc.z; vbuf[4*k4+3]=cc.w;
          }
        }
        float lnb[2]={0,0}, lnw[2]={0,0}, lnn[2]={0,0};
        if (l > 0){
          #pragma unroll
          for (int r=0;r<2;r++){
            int i = tid + r*NT;
            lnb[r] = B2[(size_t)(l-1)*HIDDEN + i];
            lnw[r] = NW2[(size_t)(l-1)*HIDDEN + i];
            lnn[r] = NB2[(size_t)(l-1)*HIDDEN + i];
          }
        }
        PIN();

        // ---- gate on previous layer's ffn --------------------------------
        if (l > 0) waitgeN(C + FF1G(0), 8, 16*l);

        // ---- build xn (layer input) redundantly ---------------------------
        float xn0, xn1;
        if (l == 0){
          float xs = XSc[0], al = ALp[0];
          xn0 = EMB[(size_t)token*HIDDEN + tid]*xs       + al*PE[(size_t)posi*HIDDEN + tid];
          xn1 = EMB[(size_t)token*HIDDEN + tid + 256]*xs + al*PE[(size_t)posi*HIDDEN + tid + 256];
        } else {
          float t0 = gld(&wx1[tid]) + lnb[0];
          float t1 = gld(&wx1[tid+256]) + lnb[1];
          const float* f2p = wf2 + (par^1)*4096;
          #pragma unroll
          for (int rg=0; rg<8; rg++){
            t0 += gld(&f2p[rg*512 + tid]);
            t1 += gld(&f2p[rg*512 + tid + 256]);
          }
          float s1 = t0 + t1, s2 = t0*t0 + t1*t1;
          bsum2(s1, s2, L.a.r8, tid);
          float mu = s1*(1.f/HIDDEN), rstd = rsqrtf(s2*(1.f/HIDDEN)-mu*mu+EPSLN);
          xn0 = (t0-mu)*rstd*lnw[0] + lnn[0];
          xn1 = (t1-mu)*rstd*lnw[1] + lnn[1];
        }
        L.a.xn[tid] = xn0; L.a.xn[tid+256] = xn1;
        if (b == 128){ gst(&wx[tid], xn0); gst(&wx[tid+256], xn1); }
        __syncthreads();

        // ---- q = (xn @ Wq_h + qb) * ISQ -----------------------------------
        {
          float qa = 0.f;
          #pragma unroll
          for (int k=0;k<64;k++) qa += L.a.xn[s5 + 8*k] * pfQ[k];
          L.a.red[s5*33 + c] = qa;
          __syncthreads();
          if (tid < 32){
            float qs = 0.f;
            #pragma unroll
            for (int k=0;k<8;k++) qs += L.a.red[k*33 + tid];
            L.a.q[tid] = (qs + qb) * ISQ;
          }
          __syncthreads();
        }

        // ---- clen chunk: wait the 4 new-token k/v producers ---------------
        if (ci == cstar){
          if (tid < 4){
            int kb = (tid>>1)*32 + 2*h + (tid&1);
            const int* fl = C + KVF(kb);
            int g = 0;
            while (ild(fl) < l+1){ if (++g > (1<<25)) break; }
          }
          __syncthreads();
        }

        // ---- scores + exp (no max-subtraction; bounded scores) ------------
        float e = 0.f;
        if (validp){
          if (isnew){
            #pragma unroll
            for (int k=0;k<16;k++){
              kbuf[k] = gld(&wkv[h*HD + dbase + k]);
              vbuf[k] = gld(&wkv[512 + h*HD + dbase + k]);
            }
          }
          float dot = 0.f;
          #pragma unroll
          for (int k=0;k<16;k++) dot += kbuf[k] * L.a.q[dbase + k];
          dot += __shfl_xor(dot, 1);
          e = expf(dot);
        } else {
          #pragma unroll
          for (int k=0;k<16;k++) vbuf[k] = 0.f;
        }
        if (half == 0) L.a.e[pl] = validp ? e : 0.f;
        #pragma unroll
        for (int k=0;k<16;k++) L.a.v[pl*33 + dbase + k] = vbuf[k];
        __syncthreads();

        // ---- S_ci ----------------------------------------------------------
        float se = (tid < 128) ? L.a.e[tid] : 0.f;
        #pragma unroll
        for (int o=32;o;o>>=1) se += __shfl_xor(se, o);
        if ((tid&63)==0) L.a.r8[tid>>6] = se;
        __syncthreads();
        const float S_ci = L.a.r8[0]+L.a.r8[1]+L.a.r8[2]+L.a.r8[3];

        // ---- o_ci (unnormalized) ------------------------------------------
        {
          const int d = tid & 31, grp = tid >> 5;
          float oacc = 0.f;
          #pragma unroll
          for (int q2=0;q2<16;q2++){ int pp = (grp<<4) + q2; oacc += L.a.e[pp] * L.a.v[pp*33 + d]; }
          L.a.red[tid] = oacc;
          __syncthreads();
          if (tid < 32){
            float o8 = 0.f;
            #pragma unroll
            for (int g=0; g<8; g++) o8 += L.a.red[tid + (g<<5)];
            L.a.o32[tid] = o8;
          }
          if (tid == 0) unsafeAtomicAdd((float*)(C + SLINE(par,h)), S_ci);
          __syncthreads();
        }

        // ---- fused out-proj: o_ci @ OW_h -> atomic into wop[par][h] -------
        {
          float a0 = 0.f, a1 = 0.f;
          #pragma unroll
          for (int d=0; d<32; d++){ a0 += L.a.o32[d]*pfO[d]; a1 += L.a.o32[d]*pfO[32+d]; }
          unsafeAtomicAdd(&wop[par*8192 + h*512 + tid], a0);
          unsafeAtomicAdd(&wop[par*8192 + h*512 + 256 + tid], a1);
        }
        done_add(&C[HEADC(h)], tid);
      }
    }
    return;
  }

  // ========================= FFN BLOCKS (0..127) ============================
  {
    const int f = b, rgrp = f >> 4;
    const bool iskv = (f < 64);
    const int mat = f >> 5;                 // 0 = k, 1 = v (for f<64)
    const int c0  = (f & 31) << 4;

    for (int l=0;l<NL;l++){
      const int par = l & 1;
      // ---- prefetch -------------------------------------------------------
      float pfKV[32]; float pfKb = 0.f;
      float lnb[2]={0,0}, lnw[2]={0,0}, lnn[2]={0,0};
      if (iskv){
        const float* Wk = QKVW + (size_t)l*HIDDEN*H3 + (size_t)(tid>>4)*H3 + HIDDEN + mat*HIDDEN + c0 + (tid&15);
        #pragma unroll
        for (int k=0;k<32;k++) pfKV[k] = Wk[(size_t)(k*16)*H3];
        pfKb = QKVB[(size_t)l*H3 + HIDDEN + mat*HIDDEN + c0 + (tid&15)];
        if (l > 0){
          #pragma unroll
          for (int r=0;r<2;r++){
            int i = tid + r*NT;
            lnb[r] = B2[(size_t)(l-1)*HIDDEN + i];
            lnw[r] = NW2[(size_t)(l-1)*HIDDEN + i];
            lnn[r] = NB2[(size_t)(l-1)*HIDDEN + i];
          }
        }
      }
      float pfF1[32];
      {
        const float* W1p = W1 + (size_t)l*HIDDEN*FFD + (size_t)(tid>>4)*FFD + f*16 + (tid&15);
        #pragma unroll
        for (int k=0;k<32;k++) pfF1[k] = W1p[(size_t)(k*16)*FFD];
      }
      float pfF2[32];
      {
        const float* W2p = W2 + (size_t)l*FFD*HIDDEN + (size_t)(f*16)*HIDDEN + tid;
        #pragma unroll
        for (int cc=0;cc<16;cc++){ pfF2[cc] = W2p[(size_t)cc*HIDDEN]; pfF2[16+cc] = W2p[(size_t)cc*HIDDEN + 256]; }
      }
      float pfOB[2], pfW1n[2], pfB1n[2];
      #pragma unroll
      for (int r=0;r<2;r++){
        int i = tid + r*NT;
        pfOB[r]  = OUTB[(size_t)l*HIDDEN + i];
        pfW1n[r] = NW1[(size_t)l*HIDDEN + i];
        pfB1n[r] = NB1[(size_t)l*HIDDEN + i];
      }
      float pfB1f = B1[(size_t)l*FFD + f*16 + (tid&15)];
      PIN();

      // ---- kv duty (f<64): new-token k/v cols -----------------------------
      if (iskv){
        if (l > 0){
          waitgeN(C + FF1G(0), 8, 16*l);
          float t0 = gld(&wx1[tid]) + lnb[0];
          float t1 = gld(&wx1[tid+256]) + lnb[1];
          const float* f2p = wf2 + (par^1)*4096;
          #pragma unroll
          for (int rg=0; rg<8; rg++){
            t0 += gld(&f2p[rg*512 + tid]);
            t1 += gld(&f2p[rg*512 + tid + 256]);
          }
          float s1 = t0 + t1, s2 = t0*t0 + t1*t1;
          bsum2(s1, s2, L.f.r8, tid);
          float mu = s1*(1.f/HIDDEN), rstd = rsqrtf(s2*(1.f/HIDDEN)-mu*mu+EPSLN);
          L.f.xn[tid]     = (t0-mu)*rstd*lnw[0] + lnn[0];
          L.f.xn[tid+256] = (t1-mu)*rstd*lnw[1] + lnn[1];
        } else {
          float xs = XSc[0], al = ALp[0];
          L.f.xn[tid]     = EMB[(size_t)token*HIDDEN + tid]*xs       + al*PE[(size_t)posi*HIDDEN + tid];
          L.f.xn[tid+256] = EMB[(size_t)token*HIDDEN + tid + 256]*xs + al*PE[(size_t)posi*HIDDEN + tid + 256];
        }
        __syncthreads();
        float dsum = dotred<32>(pfKV, L.f.xn, L.f.red, tid);
        if (tid < 16){
          int j = c0 + tid;
          float val = dsum + pfKb;
          gst(&wkv[mat*HIDDEN + j], val);
          float* dst = (mat ? VO : KO) + ((size_t)l*CAPCTX + clen)*HIDDEN + j;
          *dst = val;
        }
        __syncthreads();
        if (tid == 0) ist(&C[KVF(f)], l+1);
      }

      // ---- copy duty (hidden under attention) -----------------------------
      kvcopy(f, T_copy, l, clen, KC, VC, KO, VO, tid);

      // ---- gate on attention ----------------------------------------------
      waitgeN(C + HEADC(0), 16, nch*(l+1));

      // ---- zero next-parity accumulators (ordered: zero -> FF1G add) ------
      if (tid < 64) gst(&wop[(par^1)*8192 + (f>>3)*512 + (f&7)*64 + tid], 0.f);
      if (tid < 32) gst(&wf2[(par^1)*4096 + f*32 + tid], 0.f);
      if (f < 16 && tid == 0) gst((float*)(C + SLINE(par^1, f)), 0.f);

      // ---- LN1 build: t = wx + OUTB + sum_h wop[h]/S_h --------------------
      if (tid < 16) L.f.s16[tid] = 1.f / gld((const float*)(C + SLINE(par, tid)));
      __syncthreads();
      float t0 = gld(&wx[tid]) + pfOB[0];
      float t1 = gld(&wx[tid+256]) + pfOB[1];
      #pragma unroll
      for (int h2=0; h2<16; h2++){
        float is = L.f.s16[h2];
        t0 += gld(&wop[par*8192 + h2*512 + tid]) * is;
        t1 += gld(&wop[par*8192 + h2*512 + tid + 256]) * is;
      }
      float s1 = t0 + t1, s2 = t0*t0 + t1*t1;
      bsum2(s1, s2, L.f.r8, tid);
      float mu = s1*(1.f/HIDDEN), rstd = rsqrtf(s2*(1.f/HIDDEN)-mu*mu+EPSLN);
      float xn0 = (t0-mu)*rstd*pfW1n[0] + pfB1n[0];
      float xn1 = (t1-mu)*rstd*pfW1n[1] + pfB1n[1];
      L.f.xn[tid] = xn0; L.f.xn[tid+256] = xn1;
      if (f == 0){ gst(&wx1[tid], xn0); gst(&wx1[tid+256], xn1); }
      __syncthreads();

      // ---- ff1 (16 cols) + fused ff2 tile ---------------------------------
      float dsum = dotred<32>(pfF1, L.f.xn, L.f.red, tid);
      if (tid < 16) L.f.h16[tid] = fmaxf(dsum + pfB1f, 0.f);
      __syncthreads();
      float a0 = 0.f, a1 = 0.f;
      #pragma unroll
      for (int cc=0; cc<16; cc++){ float hv = L.f.h16[cc]; a0 += hv*pfF2[cc]; a1 += hv*pfF2[16+cc]; }
      unsafeAtomicAdd(&wf2[par*4096 + rgrp*512 + tid], a0);
      unsafeAtomicAdd(&wf2[par*4096 + rgrp*512 + 256 + tid], a1);
      done_add(&C[FF1G(rgrp)], tid);
    }

    // ---- pred logits (ffn blocks 0..64) ------------------------------------
    if (f < 65){
      const int v0 = f << 4;
      const int nrows = (f == 64) ? 1 : 16;
      const int rr = tid >> 4, s2l = tid & 15;
      float pfP[32]; float pfPb = 0.f;
      if (rr < nrows){
        const float* row = PW + (size_t)(v0+rr)*HIDDEN;
        #pragma unroll
        for (int mm=0; mm<32; mm++) pfP[mm] = row[s2l + (mm<<4)];
        pfPb = PB[v0+rr];
      }
      float lnb[2], lnw[2], lnn[2];
      #pragma unroll
      for (int r=0;r<2;r++){
        int i = tid + r*NT;
        lnb[r] = B2[(size_t)(NL-1)*HIDDEN + i];
        lnw[r] = NW2[(size_t)(NL-1)*HIDDEN + i];
        lnn[r] = NB2[(size_t)(NL-1)*HIDDEN + i];
      }
      PIN();
      waitgeN(C + FF1G(0), 8, 16*NL);
      float t0 = gld(&wx1[tid]) + lnb[0];
      float t1 = gld(&wx1[tid+256]) + lnb[1];
      const float* f2p = wf2 + 4096;        // layer-23 parity = 1
      #pragma unroll
      for (int rg=0; rg<8; rg++){
        t0 += gld(&f2p[rg*512 + tid]);
        t1 += gld(&f2p[rg*512 + tid + 256]);
      }
      float s1 = t0 + t1, s2 = t0*t0 + t1*t1;
      bsum2(s1, s2, L.f.r8, tid);
      float mu = s1*(1.f/HIDDEN), rstd = rsqrtf(s2*(1.f/HIDDEN)-mu*mu+EPSLN);
      L.f.xn[tid]     = (t0-mu)*rstd*lnw[0] + lnn[0];
      L.f.xn[tid+256] = (t1-mu)*rstd*lnw[1] + lnn[1];
      __syncthreads();
      if (rr < nrows){
        float acc = 0.f;
        #pragma unroll
        for (int mm=0; mm<32; mm++) acc += L.f.xn[s2l + (mm<<4)] * pfP[mm];
        #pragma unroll
        for (int o=1;o<16;o<<=1) acc += __shfl_xor(acc, o);
        if (s2l == 0) gst(&OUT[v0+rr], acc + pfPb);
      }
      done_add(&C[PRED_C], tid);
    }

    // ---- final: argmax + scalars (block 0) ---------------------------------
    if (b == 0){
      waitge1(&C[PRED_C], 65);
      float bv = -3.0e38f; int bi = 0;
      for (int v=tid; v<NVOCAB; v+=NT){
        float x = gld(&OUT[v]);
        if (x > bv){ bv = x; bi = v; }
      }
      L.f.xn[tid] = bv;
      ((int*)&L.f.xn[256])[tid] = bi;
      __syncthreads();
      for (int step=128; step; step>>=1){
        if (tid < step){
          float ov2 = L.f.xn[tid+step]; int oi = ((int*)&L.f.xn[256])[tid+step];
          float mv  = L.f.xn[tid];      int mi = ((int*)&L.f.xn[256])[tid];
          if (ov2 > mv || (ov2 == mv && oi < mi)){ L.f.xn[tid]=ov2; ((int*)&L.f.xn[256])[tid]=oi; }
        }
        __syncthreads();
      }
      if (tid == 0){
        int bi0 = ((int*)&L.f.xn[256])[0];
        OUT[NVOCAB]   = (float)bi0;
        OUT[NVOCAB+1] = (bi0 == 1024) ? 1.f : 0.f;
        OUT[NVOCAB+2] = (float)nlen;
        OUT[NVOCAB+3] = (float)(posi + 1);
      }
    }
  }
}

extern "C" void kernel_launch(void* const* d_in, const int* in_sizes, int n_in,
                              void* d_out, int out_size, void* d_ws, size_t ws_size,
                              hipStream_t stream) {
  (void)in_sizes; (void)n_in; (void)out_size; (void)ws_size;
  // zero counters/S (8192 B) + wop (65536 B) + wf2 (32768 B)
  hipMemsetAsync(d_ws, 0, 8192 + 65536 + 32768, stream);
  t2s_decode<<<GRID, NT, 0, stream>>>(
    (const int*)d_in[0], (const int*)d_in[1], (const int*)d_in[2],
    (const float*)d_in[3], (const float*)d_in[4],
    (const float*)d_in[5], (const float*)d_in[6],
    (const float*)d_in[7], (const float*)d_in[8],
    (const float*)d_in[9], (const float*)d_in[10],
    (const float*)d_in[11], (const float*)d_in[12],
    (const float*)d_in[13], (const float*)d_in[14],
    (const float*)d_in[15], (const float*)d_in[16],
    (const float*)d_in[17], (const float*)d_in[18],
    (const float*)d_in[19], (const float*)d_in[20],
    (const float*)d_in[21], (const float*)d_in[22],
    (float*)d_out, (float*)d_ws);
}